// Round 1
// baseline (1213.001 us; speedup 1.0000x reference)
//
#include <hip/hip_runtime.h>

typedef unsigned short u16;
typedef __bf16 bf16x8 __attribute__((ext_vector_type(8)));
typedef __bf16 bf16x4 __attribute__((ext_vector_type(4)));
typedef float  f32x4  __attribute__((ext_vector_type(4)));

#define BN_EPS 1e-5f

__device__ __forceinline__ float mish_f(float x) {
    // mish(x) = x * tanh(softplus(x)) = x * (u^2+2u)/(u^2+2u+2), u = e^x
    float xc = fminf(fmaxf(x, -30.0f), 30.0f);
    float u = __expf(xc);
    float num = u * (u + 2.0f);
    return x * __fdividef(num, num + 2.0f);
}

// ---------------- prep: x fp32 -> bf16 ----------------
__global__ void prep_x_kernel(const float* __restrict__ x, __bf16* __restrict__ xbf, int total4) {
    int i = blockIdx.x * blockDim.x + threadIdx.x;
    if (i >= total4) return;
    float4 v = reinterpret_cast<const float4*>(x)[i];
    bf16x4 o;
    o[0] = (__bf16)v.x; o[1] = (__bf16)v.y; o[2] = (__bf16)v.z; o[3] = (__bf16)v.w;
    *reinterpret_cast<bf16x4*>(xbf + (size_t)i * 4) = o;
}

// ---------------- prep: weights -> B^T bf16 layouts ----------------
// W1T[128][256], W2T[128][128], WeT[128][160] (k in 144..159 zero-padded)
__global__ void prep_w_kernel(const float* __restrict__ W1, const float* __restrict__ W2,
                              const float* __restrict__ We,
                              __bf16* __restrict__ W1T, __bf16* __restrict__ W2T,
                              __bf16* __restrict__ WeT) {
    int i = blockIdx.x * blockDim.x + threadIdx.x;
    if (i < 128 * 256) {
        int n = i >> 8, k = i & 255;
        W1T[n * 256 + k] = (__bf16)W1[k * 128 + n];
    } else if (i < 128 * 256 + 128 * 128) {
        int j = i - 128 * 256;
        int n = j >> 7, k = j & 127;
        W2T[n * 128 + k] = (__bf16)W2[k * 128 + n];
    } else if (i < 128 * 256 + 128 * 128 + 128 * 160) {
        int j = i - (128 * 256 + 128 * 128);
        int n = j / 160, k = j - n * 160;
        WeT[n * 160 + k] = (k < 144) ? (__bf16)We[k * 128 + n] : (__bf16)0.0f;
    }
}

// ---------------- main edge kernel: one wave per 16-edge tile ----------------
// h_n = mish(cat(x_i,x_j)@W1 + b1)@W2 + b2 ; h_e = mish(cat(eattr,x_j)@We + be)
// atomicAdd(aggr[dst], h_n * h_e)
// MFMA 16x16x32 layouts (verified, learn_hip m89/m118):
//   A: lane holds A[m = lane&15][k = (lane>>4)*8 + j]
//   B: lane holds B[k = (lane>>4)*8 + j][n = lane&15]  (load from B^T rows)
//   C/D: reg r holds D[row = (lane>>4)*4 + r][col = lane&15]
__global__ __launch_bounds__(256) void edge_kernel(
    const __bf16* __restrict__ xbf,
    const int* __restrict__ eidx,     // [2][E], row0=src(j), row1=dst(i)
    const float* __restrict__ eattr,  // [E][16]
    const __bf16* __restrict__ W1T, const float* __restrict__ b1,
    const __bf16* __restrict__ W2T, const float* __restrict__ b2,
    const __bf16* __restrict__ WeT, const float* __restrict__ be,
    float* __restrict__ aggr, int E_)
{
    __shared__ __align__(16) __bf16 h1s[4][16][136];  // +8 pad: 2-way (free) LDS conflicts
    const int wid  = threadIdx.x >> 6;
    const int lane = threadIdx.x & 63;
    const int quad = lane >> 4;
    const int l16  = lane & 15;

    const int tile = blockIdx.x * 4 + wid;
    const int e0   = tile * 16;

    // this lane's gather row (m = l16)
    int em = e0 + l16; if (em > E_ - 1) em = E_ - 1;
    const int src_m = eidx[em];        // j
    const int dst_m = eidx[E_ + em];   // i

    const f32x4 fz4 = {0.f, 0.f, 0.f, 0.f};

    // ---- GEMM1: cat(x_i, x_j) @ W1, K=256 ----
    f32x4 accn[8];
    #pragma unroll
    for (int nt = 0; nt < 8; ++nt) accn[nt] = fz4;

    #pragma unroll
    for (int kt = 0; kt < 8; ++kt) {
        const int gk = kt * 32 + quad * 8;
        const __bf16* ap = (gk < 128) ? (xbf + (size_t)dst_m * 128 + gk)
                                      : (xbf + (size_t)src_m * 128 + (gk - 128));
        bf16x8 a = *reinterpret_cast<const bf16x8*>(ap);
        #pragma unroll
        for (int nt = 0; nt < 8; ++nt) {
            bf16x8 b = *reinterpret_cast<const bf16x8*>(W1T + (nt * 16 + l16) * 256 + gk);
            accn[nt] = __builtin_amdgcn_mfma_f32_16x16x32_bf16(a, b, accn[nt], 0, 0, 0);
        }
    }
    // bias + mish -> LDS in row-major [edge][channel] (bf16)
    #pragma unroll
    for (int nt = 0; nt < 8; ++nt) {
        float bb = b1[nt * 16 + l16];
        #pragma unroll
        for (int r = 0; r < 4; ++r) {
            float v = mish_f(accn[nt][r] + bb);
            h1s[wid][quad * 4 + r][nt * 16 + l16] = (__bf16)v;
        }
    }
    __syncthreads();

    // ---- GEMM_e: cat(eattr, x_j, 0-pad) @ We, K=160 (144 real) ----
    f32x4 acce[8];
    #pragma unroll
    for (int nt = 0; nt < 8; ++nt) acce[nt] = fz4;

    #pragma unroll
    for (int kt = 0; kt < 5; ++kt) {
        const int gk = kt * 32 + quad * 8;
        bf16x8 a;
        if (gk < 16) {
            const float4* p = reinterpret_cast<const float4*>(eattr + (size_t)em * 16 + gk);
            float4 v0 = p[0], v1 = p[1];
            a[0] = (__bf16)v0.x; a[1] = (__bf16)v0.y; a[2] = (__bf16)v0.z; a[3] = (__bf16)v0.w;
            a[4] = (__bf16)v1.x; a[5] = (__bf16)v1.y; a[6] = (__bf16)v1.z; a[7] = (__bf16)v1.w;
        } else if (gk < 144) {
            a = *reinterpret_cast<const bf16x8*>(xbf + (size_t)src_m * 128 + (gk - 16));
        } else {
            #pragma unroll
            for (int j = 0; j < 8; ++j) a[j] = (__bf16)0.0f;
        }
        #pragma unroll
        for (int nt = 0; nt < 8; ++nt) {
            bf16x8 b = *reinterpret_cast<const bf16x8*>(WeT + (nt * 16 + l16) * 160 + gk);
            acce[nt] = __builtin_amdgcn_mfma_f32_16x16x32_bf16(a, b, acce[nt], 0, 0, 0);
        }
    }
    // h_e = mish(acce + be), keep in registers (C layout)
    #pragma unroll
    for (int nt = 0; nt < 8; ++nt) {
        float bb = be[nt * 16 + l16];
        #pragma unroll
        for (int r = 0; r < 4; ++r) acce[nt][r] = mish_f(acce[nt][r] + bb);
    }

    // ---- GEMM2: mish(h1) @ W2, K=128, A from LDS ----
    f32x4 acc2[8];
    #pragma unroll
    for (int nt = 0; nt < 8; ++nt) acc2[nt] = fz4;

    const __bf16* hrow = &h1s[wid][l16][0];
    #pragma unroll
    for (int kt = 0; kt < 4; ++kt) {
        const int gk = kt * 32 + quad * 8;
        bf16x8 a = *reinterpret_cast<const bf16x8*>(hrow + gk);
        #pragma unroll
        for (int nt = 0; nt < 8; ++nt) {
            bf16x8 b = *reinterpret_cast<const bf16x8*>(W2T + (nt * 16 + l16) * 128 + gk);
            acc2[nt] = __builtin_amdgcn_mfma_f32_16x16x32_bf16(a, b, acc2[nt], 0, 0, 0);
        }
    }

    // ---- epilogue: msg = (h1@W2 + b2) * h_e, scatter-add by dst ----
    int dstrow[4]; bool valid[4];
    #pragma unroll
    for (int r = 0; r < 4; ++r) {
        int er = e0 + quad * 4 + r;
        valid[r] = (er < E_);
        int erc = valid[r] ? er : (E_ - 1);
        dstrow[r] = eidx[E_ + erc];
    }
    #pragma unroll
    for (int nt = 0; nt < 8; ++nt) {
        float bb2 = b2[nt * 16 + l16];
        #pragma unroll
        for (int r = 0; r < 4; ++r) {
            float msg = (acc2[nt][r] + bb2) * acce[nt][r];
            if (valid[r]) atomicAdd(aggr + (size_t)dstrow[r] * 128 + nt * 16 + l16, msg);
        }
    }
}

// ---------------- node kernel: out = aggr + x@Wroot + bias; BN partial sums ----------------
__global__ __launch_bounds__(256) void node_kernel(
    const float* __restrict__ x, const float* __restrict__ Wroot,
    const float* __restrict__ bias, float* __restrict__ out,
    float* __restrict__ stats, int N_)
{
    __shared__ float xs[16][128];
    __shared__ float red[2][2][128];
    const int n0 = blockIdx.x * 16;

    for (int i = threadIdx.x; i < 512; i += 256) {
        int row = i >> 5, col4 = i & 31;
        int n = n0 + row;
        float4 v = {0.f, 0.f, 0.f, 0.f};
        if (n < N_) v = reinterpret_cast<const float4*>(x)[(size_t)n * 32 + col4];
        *reinterpret_cast<float4*>(&xs[row][col4 * 4]) = v;
    }
    __syncthreads();

    const int c = threadIdx.x & 127;
    const int h = threadIdx.x >> 7;
    float acc[8];
    #pragma unroll
    for (int r = 0; r < 8; ++r) acc[r] = 0.f;
    for (int k = 0; k < 128; ++k) {
        float w = Wroot[k * 128 + c];
        #pragma unroll
        for (int r = 0; r < 8; ++r) acc[r] += xs[h * 8 + r][k] * w;
    }
    float bc = bias[c];
    float bsum = 0.f, bsq = 0.f;
    #pragma unroll
    for (int r = 0; r < 8; ++r) {
        int n = n0 + h * 8 + r;
        if (n < N_) {
            size_t o = (size_t)n * 128 + c;
            float pre = out[o] + acc[r] + bc;
            out[o] = pre;
            bsum += pre; bsq += pre * pre;
        }
    }
    red[0][h][c] = bsum; red[1][h][c] = bsq;
    __syncthreads();
    if (h == 0) {
        atomicAdd(&stats[c],       red[0][0][c] + red[0][1][c]);
        atomicAdd(&stats[128 + c], red[1][0][c] + red[1][1][c]);
    }
}

// ---------------- BN finalize ----------------
__global__ void bn_kernel(float* __restrict__ out, const float* __restrict__ stats,
                          const float* __restrict__ gamma, const float* __restrict__ beta,
                          float invN, int total4)
{
    int i = blockIdx.x * blockDim.x + threadIdx.x;
    if (i >= total4) return;
    int c0 = (i & 31) * 4;
    float4 v = reinterpret_cast<float4*>(out)[i];
    float o[4] = {v.x, v.y, v.z, v.w};
    #pragma unroll
    for (int j = 0; j < 4; ++j) {
        int c = c0 + j;
        float mean  = stats[c] * invN;
        float var   = stats[128 + c] * invN - mean * mean;
        float scale = gamma[c] * rsqrtf(var + BN_EPS);
        o[j] = (o[j] - mean) * scale + beta[c];
    }
    v.x = o[0]; v.y = o[1]; v.z = o[2]; v.w = o[3];
    reinterpret_cast<float4*>(out)[i] = v;
}

extern "C" void kernel_launch(void* const* d_in, const int* in_sizes, int n_in,
                              void* d_out, int out_size, void* d_ws, size_t ws_size,
                              hipStream_t stream)
{
    const float* x     = (const float*)d_in[0];
    const int*   eidx  = (const int*)d_in[1];
    const float* eattr = (const float*)d_in[2];
    const float* W1    = (const float*)d_in[3];
    const float* b1    = (const float*)d_in[4];
    const float* W2    = (const float*)d_in[5];
    const float* b2    = (const float*)d_in[6];
    const float* We    = (const float*)d_in[7];
    const float* be    = (const float*)d_in[8];
    const float* Wroot = (const float*)d_in[9];
    const float* bias  = (const float*)d_in[10];
    const float* gamma = (const float*)d_in[11];
    const float* beta  = (const float*)d_in[12];

    const int N_ = in_sizes[0] / 128;
    const int E_ = in_sizes[1] / 2;

    char* ws = (char*)d_ws;
    __bf16* xbf = (__bf16*)ws;
    size_t off = (size_t)N_ * 128 * 2;
    __bf16* W1T = (__bf16*)(ws + off); off += 128 * 256 * 2;
    __bf16* W2T = (__bf16*)(ws + off); off += 128 * 128 * 2;
    __bf16* WeT = (__bf16*)(ws + off); off += 128 * 160 * 2;
    float* stats = (float*)(ws + off);

    float* out = (float*)d_out;

    hipMemsetAsync(out, 0, (size_t)out_size * sizeof(float), stream);
    hipMemsetAsync(stats, 0, 256 * sizeof(float), stream);

    int total4 = N_ * 32;
    prep_x_kernel<<<(total4 + 255) / 256, 256, 0, stream>>>(x, xbf, total4);
    int wtot = 128 * 256 + 128 * 128 + 128 * 160;
    prep_w_kernel<<<(wtot + 255) / 256, 256, 0, stream>>>(W1, W2, We, W1T, W2T, WeT);

    int tiles = (E_ + 15) / 16;
    int eblocks = (tiles + 3) / 4;
    edge_kernel<<<eblocks, 256, 0, stream>>>(xbf, eidx, eattr, W1T, b1, W2T, b2, WeT, be, out, E_);

    node_kernel<<<(N_ + 15) / 16, 256, 0, stream>>>(x, Wroot, bias, out, stats, N_);

    bn_kernel<<<(total4 + 255) / 256, 256, 0, stream>>>(out, stats, gamma, beta, 1.0f / (float)N_, total4);
}

// Round 2
// 1107.857 us; speedup vs baseline: 1.0949x; 1.0949x over previous
//
#include <hip/hip_runtime.h>

typedef __bf16 bf16x8 __attribute__((ext_vector_type(8)));
typedef __bf16 bf16x4 __attribute__((ext_vector_type(4)));
typedef float  f32x4  __attribute__((ext_vector_type(4)));

#define BN_EPS 1e-5f

__device__ __forceinline__ float mish_f(float x) {
    float xc = fminf(fmaxf(x, -30.0f), 30.0f);
    float u = __expf(xc);
    float num = u * (u + 2.0f);
    return x * __fdividef(num, num + 2.0f);
}

// ---------------- prep: x fp32 -> bf16 ----------------
__global__ void prep_x_kernel(const float* __restrict__ x, __bf16* __restrict__ xbf, int total4) {
    int i = blockIdx.x * blockDim.x + threadIdx.x;
    if (i >= total4) return;
    float4 v = reinterpret_cast<const float4*>(x)[i];
    bf16x4 o;
    o[0] = (__bf16)v.x; o[1] = (__bf16)v.y; o[2] = (__bf16)v.z; o[3] = (__bf16)v.w;
    *reinterpret_cast<bf16x4*>(xbf + (size_t)i * 4) = o;
}

// ---------------- prep: weights -> B^T bf16 ----------------
// W1T[128][256], W2T[128][128], WeT[128][160] (pad), WrT[128][128]
__global__ void prep_w_kernel(const float* __restrict__ W1, const float* __restrict__ W2,
                              const float* __restrict__ We, const float* __restrict__ Wr,
                              __bf16* __restrict__ W1T, __bf16* __restrict__ W2T,
                              __bf16* __restrict__ WeT, __bf16* __restrict__ WrT) {
    int i = blockIdx.x * blockDim.x + threadIdx.x;
    if (i < 128 * 256) {
        int n = i >> 8, k = i & 255;
        W1T[n * 256 + k] = (__bf16)W1[k * 128 + n];
    } else if (i < 128 * 256 + 128 * 128) {
        int j = i - 128 * 256;
        int n = j >> 7, k = j & 127;
        W2T[n * 128 + k] = (__bf16)W2[k * 128 + n];
    } else if (i < 128 * 256 + 128 * 128 + 128 * 160) {
        int j = i - (128 * 256 + 128 * 128);
        int n = j / 160, k = j - n * 160;
        WeT[n * 160 + k] = (k < 144) ? (__bf16)We[k * 128 + n] : (__bf16)0.0f;
    } else if (i < 128 * 256 + 128 * 128 + 128 * 160 + 128 * 128) {
        int j = i - (128 * 256 + 128 * 128 + 128 * 160);
        int n = j >> 7, k = j & 127;
        WrT[n * 128 + k] = (__bf16)Wr[k * 128 + n];
    }
}

// ---------------- counting sort by dst ----------------
__global__ void hist_kernel(const int* __restrict__ eidx, int* __restrict__ count, int E_) {
    int e = blockIdx.x * blockDim.x + threadIdx.x;
    if (e < E_) atomicAdd(&count[eidx[E_ + e]], 1);
}

__global__ __launch_bounds__(1024) void scan_kernel(const int* __restrict__ count,
                                                    int* __restrict__ cursor, int Nn) {
    __shared__ int part[1024];
    const int t = threadIdx.x;
    const int chunk = (Nn + 1023) >> 10;
    const int lo = t * chunk;
    const int hi = min(lo + chunk, Nn);
    int s = 0;
    for (int i = lo; i < hi; ++i) s += count[i];
    part[t] = s;
    __syncthreads();
    for (int off = 1; off < 1024; off <<= 1) {
        int v = (t >= off) ? part[t - off] : 0;
        __syncthreads();
        part[t] += v;
        __syncthreads();
    }
    int run = (t == 0) ? 0 : part[t - 1];  // exclusive prefix of this chunk
    for (int i = lo; i < hi; ++i) { cursor[i] = run; run += count[i]; }
}

__global__ void scatter_kernel(const int* __restrict__ eidx, int* __restrict__ cursor,
                               int* __restrict__ dstS, int* __restrict__ srcS,
                               int* __restrict__ perm, int E_) {
    int e = blockIdx.x * blockDim.x + threadIdx.x;
    if (e >= E_) return;
    int d = eidx[E_ + e];
    int p = atomicAdd(&cursor[d], 1);
    dstS[p] = d;
    srcS[p] = eidx[e];
    perm[p] = e;
}

// ---------------- main edge kernel: one wave per 16 SORTED edges ----------------
// MFMA 16x16x32 layouts:
//   A: lane holds A[m = lane&15][k = (lane>>4)*8 + j]
//   B: lane holds B[k = (lane>>4)*8 + j][n = lane&15]  (load from B^T rows)
//   C/D: reg r holds D[row = (lane>>4)*4 + r][col = lane&15]
__global__ __launch_bounds__(256) void edge_kernel(
    const __bf16* __restrict__ xbf,
    const int* __restrict__ dstS, const int* __restrict__ srcS, const int* __restrict__ perm,
    const float* __restrict__ eattr,
    const __bf16* __restrict__ W1T, const float* __restrict__ b1,
    const __bf16* __restrict__ W2T, const float* __restrict__ b2,
    const __bf16* __restrict__ WeT, const float* __restrict__ be,
    float* __restrict__ aggr, int E_)
{
    __shared__ __align__(16) __bf16 h1s[4][16][136];   // +8 pad
    __shared__ float msgS[4][16][132];                 // +4 pad: 2-way (free) banks
    __shared__ int dsts[4][16];

    const int wid  = threadIdx.x >> 6;
    const int lane = threadIdx.x & 63;
    const int quad = lane >> 4;
    const int l16  = lane & 15;

    const int tile = blockIdx.x * 4 + wid;
    const int e0   = tile * 16;

    int em = e0 + l16; if (em > E_ - 1) em = E_ - 1;
    const int src_m = srcS[em];
    const int dst_m = dstS[em];
    const int pm    = perm[em];
    if (quad == 0) dsts[wid][l16] = dst_m;

    const f32x4 fz4 = {0.f, 0.f, 0.f, 0.f};

    // ---- GEMM1: cat(x_i, x_j) @ W1, K=256 ----
    f32x4 accn[8];
    #pragma unroll
    for (int nt = 0; nt < 8; ++nt) accn[nt] = fz4;
    #pragma unroll
    for (int kt = 0; kt < 8; ++kt) {
        const int gk = kt * 32 + quad * 8;
        const __bf16* ap = (gk < 128) ? (xbf + (size_t)dst_m * 128 + gk)
                                      : (xbf + (size_t)src_m * 128 + (gk - 128));
        bf16x8 a = *reinterpret_cast<const bf16x8*>(ap);
        #pragma unroll
        for (int nt = 0; nt < 8; ++nt) {
            bf16x8 b = *reinterpret_cast<const bf16x8*>(W1T + (nt * 16 + l16) * 256 + gk);
            accn[nt] = __builtin_amdgcn_mfma_f32_16x16x32_bf16(a, b, accn[nt], 0, 0, 0);
        }
    }
    #pragma unroll
    for (int nt = 0; nt < 8; ++nt) {
        float bb = b1[nt * 16 + l16];
        #pragma unroll
        for (int r = 0; r < 4; ++r) {
            float v = mish_f(accn[nt][r] + bb);
            h1s[wid][quad * 4 + r][nt * 16 + l16] = (__bf16)v;
        }
    }
    __syncthreads();

    // ---- GEMM_e: cat(eattr, x_j, 0-pad) @ We, K=160 (144 real) ----
    f32x4 acce[8];
    #pragma unroll
    for (int nt = 0; nt < 8; ++nt) acce[nt] = fz4;
    #pragma unroll
    for (int kt = 0; kt < 5; ++kt) {
        const int gk = kt * 32 + quad * 8;
        bf16x8 a;
        if (gk < 16) {
            const float4* p = reinterpret_cast<const float4*>(eattr + (size_t)pm * 16 + gk);
            float4 v0 = p[0], v1 = p[1];
            a[0] = (__bf16)v0.x; a[1] = (__bf16)v0.y; a[2] = (__bf16)v0.z; a[3] = (__bf16)v0.w;
            a[4] = (__bf16)v1.x; a[5] = (__bf16)v1.y; a[6] = (__bf16)v1.z; a[7] = (__bf16)v1.w;
        } else if (gk < 144) {
            a = *reinterpret_cast<const bf16x8*>(xbf + (size_t)src_m * 128 + (gk - 16));
        } else {
            #pragma unroll
            for (int j = 0; j < 8; ++j) a[j] = (__bf16)0.0f;
        }
        #pragma unroll
        for (int nt = 0; nt < 8; ++nt) {
            bf16x8 b = *reinterpret_cast<const bf16x8*>(WeT + (nt * 16 + l16) * 160 + gk);
            acce[nt] = __builtin_amdgcn_mfma_f32_16x16x32_bf16(a, b, acce[nt], 0, 0, 0);
        }
    }
    #pragma unroll
    for (int nt = 0; nt < 8; ++nt) {
        float bb = be[nt * 16 + l16];
        #pragma unroll
        for (int r = 0; r < 4; ++r) acce[nt][r] = mish_f(acce[nt][r] + bb);
    }

    // ---- GEMM2: mish(h1) @ W2, K=128 ----
    f32x4 acc2[8];
    #pragma unroll
    for (int nt = 0; nt < 8; ++nt) acc2[nt] = fz4;
    const __bf16* hrow = &h1s[wid][l16][0];
    #pragma unroll
    for (int kt = 0; kt < 4; ++kt) {
        const int gk = kt * 32 + quad * 8;
        bf16x8 a = *reinterpret_cast<const bf16x8*>(hrow + gk);
        #pragma unroll
        for (int nt = 0; nt < 8; ++nt) {
            bf16x8 b = *reinterpret_cast<const bf16x8*>(W2T + (nt * 16 + l16) * 128 + gk);
            acc2[nt] = __builtin_amdgcn_mfma_f32_16x16x32_bf16(a, b, acc2[nt], 0, 0, 0);
        }
    }

    // ---- msg -> LDS (zero invalid rows), then segment-reduce sorted runs ----
    bool valid[4];
    #pragma unroll
    for (int r = 0; r < 4; ++r) valid[r] = (e0 + quad * 4 + r) < E_;
    #pragma unroll
    for (int nt = 0; nt < 8; ++nt) {
        float bb2 = b2[nt * 16 + l16];
        #pragma unroll
        for (int r = 0; r < 4; ++r) {
            float msg = (acc2[nt][r] + bb2) * acce[nt][r];
            msgS[wid][quad * 4 + r][nt * 16 + l16] = valid[r] ? msg : 0.0f;
        }
    }
    __syncthreads();

    // 64 lanes x 2 channels each; runs of equal dst are wave-uniform branches
    const int c0 = lane, c1 = lane + 64;
    float a0 = msgS[wid][0][c0], a1 = msgS[wid][0][c1];
    int d = dsts[wid][0];
    #pragma unroll
    for (int e = 1; e < 16; ++e) {
        int dn = dsts[wid][e];
        float m0 = msgS[wid][e][c0], m1 = msgS[wid][e][c1];
        if (dn != d) {
            atomicAdd(aggr + (size_t)d * 128 + c0, a0);
            atomicAdd(aggr + (size_t)d * 128 + c1, a1);
            a0 = m0; a1 = m1; d = dn;
        } else {
            a0 += m0; a1 += m1;
        }
    }
    atomicAdd(aggr + (size_t)d * 128 + c0, a0);
    atomicAdd(aggr + (size_t)d * 128 + c1, a1);
}

// ---------------- node kernel (MFMA): out = aggr + x@Wroot + bias; BN partials ----------------
__global__ __launch_bounds__(256) void node_kernel(
    const __bf16* __restrict__ xbf, const __bf16* __restrict__ WrT,
    const float* __restrict__ bias, float* __restrict__ out,
    float* __restrict__ stats, int N_)
{
    __shared__ float lsum[128], lsq[128];
    const int wid  = threadIdx.x >> 6;
    const int lane = threadIdx.x & 63;
    const int quad = lane >> 4;
    const int l16  = lane & 15;
    const int n0   = (blockIdx.x * 4 + wid) * 16;

    if (threadIdx.x < 128) { lsum[threadIdx.x] = 0.f; lsq[threadIdx.x] = 0.f; }
    __syncthreads();

    int nm = n0 + l16; if (nm > N_ - 1) nm = N_ - 1;

    const f32x4 fz4 = {0.f, 0.f, 0.f, 0.f};
    f32x4 acc[8];
    #pragma unroll
    for (int nt = 0; nt < 8; ++nt) acc[nt] = fz4;
    #pragma unroll
    for (int kt = 0; kt < 4; ++kt) {
        const int gk = kt * 32 + quad * 8;
        bf16x8 a = *reinterpret_cast<const bf16x8*>(xbf + (size_t)nm * 128 + gk);
        #pragma unroll
        for (int nt = 0; nt < 8; ++nt) {
            bf16x8 b = *reinterpret_cast<const bf16x8*>(WrT + (nt * 16 + l16) * 128 + gk);
            acc[nt] = __builtin_amdgcn_mfma_f32_16x16x32_bf16(a, b, acc[nt], 0, 0, 0);
        }
    }

    #pragma unroll
    for (int nt = 0; nt < 8; ++nt) {
        const int c = nt * 16 + l16;
        float bc = bias[c];
        float ps = 0.f, pq = 0.f;
        #pragma unroll
        for (int r = 0; r < 4; ++r) {
            int n = n0 + quad * 4 + r;
            if (n < N_) {
                size_t o = (size_t)n * 128 + c;
                float pre = out[o] + acc[nt][r] + bc;
                out[o] = pre;
                ps += pre; pq += pre * pre;
            }
        }
        atomicAdd(&lsum[c], ps);
        atomicAdd(&lsq[c], pq);
    }
    __syncthreads();
    if (threadIdx.x < 128) {
        atomicAdd(&stats[threadIdx.x],       lsum[threadIdx.x]);
        atomicAdd(&stats[128 + threadIdx.x], lsq[threadIdx.x]);
    }
}

// ---------------- BN finalize ----------------
__global__ void bn_kernel(float* __restrict__ out, const float* __restrict__ stats,
                          const float* __restrict__ gamma, const float* __restrict__ beta,
                          float invN, int total4)
{
    int i = blockIdx.x * blockDim.x + threadIdx.x;
    if (i >= total4) return;
    int c0 = (i & 31) * 4;
    float4 v = reinterpret_cast<float4*>(out)[i];
    float o[4] = {v.x, v.y, v.z, v.w};
    #pragma unroll
    for (int j = 0; j < 4; ++j) {
        int c = c0 + j;
        float mean  = stats[c] * invN;
        float var   = stats[128 + c] * invN - mean * mean;
        float scale = gamma[c] * rsqrtf(var + BN_EPS);
        o[j] = (o[j] - mean) * scale + beta[c];
    }
    v.x = o[0]; v.y = o[1]; v.z = o[2]; v.w = o[3];
    reinterpret_cast<float4*>(out)[i] = v;
}

extern "C" void kernel_launch(void* const* d_in, const int* in_sizes, int n_in,
                              void* d_out, int out_size, void* d_ws, size_t ws_size,
                              hipStream_t stream)
{
    const float* x     = (const float*)d_in[0];
    const int*   eidx  = (const int*)d_in[1];
    const float* eattr = (const float*)d_in[2];
    const float* W1    = (const float*)d_in[3];
    const float* b1    = (const float*)d_in[4];
    const float* W2    = (const float*)d_in[5];
    const float* b2    = (const float*)d_in[6];
    const float* We    = (const float*)d_in[7];
    const float* be    = (const float*)d_in[8];
    const float* Wroot = (const float*)d_in[9];
    const float* bias  = (const float*)d_in[10];
    const float* gamma = (const float*)d_in[11];
    const float* beta  = (const float*)d_in[12];

    const int N_ = in_sizes[0] / 128;
    const int E_ = in_sizes[1] / 2;

    char* ws = (char*)d_ws;
    size_t off = 0;
    __bf16* xbf = (__bf16*)(ws + off); off += (size_t)N_ * 128 * 2;
    __bf16* W1T = (__bf16*)(ws + off); off += 128 * 256 * 2;
    __bf16* W2T = (__bf16*)(ws + off); off += 128 * 128 * 2;
    __bf16* WeT = (__bf16*)(ws + off); off += 128 * 160 * 2;
    __bf16* WrT = (__bf16*)(ws + off); off += 128 * 128 * 2;
    float* stats = (float*)(ws + off); off += 256 * 4;
    off = (off + 15) & ~(size_t)15;
    int* count  = (int*)(ws + off); off += (size_t)N_ * 4;
    int* cursor = (int*)(ws + off); off += (size_t)N_ * 4;
    int* dstS   = (int*)(ws + off); off += (size_t)E_ * 4;
    int* srcS   = (int*)(ws + off); off += (size_t)E_ * 4;
    int* perm   = (int*)(ws + off); off += (size_t)E_ * 4;

    float* out = (float*)d_out;

    hipMemsetAsync(out, 0, (size_t)out_size * sizeof(float), stream);
    hipMemsetAsync(stats, 0, 256 * sizeof(float), stream);
    hipMemsetAsync(count, 0, (size_t)N_ * sizeof(int), stream);

    int total4 = N_ * 32;
    prep_x_kernel<<<(total4 + 255) / 256, 256, 0, stream>>>(x, xbf, total4);
    int wtot = 128 * 256 + 128 * 128 + 128 * 160 + 128 * 128;
    prep_w_kernel<<<(wtot + 255) / 256, 256, 0, stream>>>(W1, W2, We, Wroot, W1T, W2T, WeT, WrT);

    hist_kernel<<<(E_ + 255) / 256, 256, 0, stream>>>(eidx, count, E_);
    scan_kernel<<<1, 1024, 0, stream>>>(count, cursor, N_);
    scatter_kernel<<<(E_ + 255) / 256, 256, 0, stream>>>(eidx, cursor, dstS, srcS, perm, E_);

    int tiles = (E_ + 15) / 16;
    edge_kernel<<<(tiles + 3) / 4, 256, 0, stream>>>(xbf, dstS, srcS, perm, eattr,
                                                     W1T, b1, W2T, b2, WeT, be, out, E_);

    int ntiles = (N_ + 15) / 16;
    node_kernel<<<(ntiles + 3) / 4, 256, 0, stream>>>(xbf, WrT, bias, out, stats, N_);

    bn_kernel<<<(total4 + 255) / 256, 256, 0, stream>>>(out, stats, gamma, beta, 1.0f / (float)N_, total4);
}

// Round 3
// 840.079 us; speedup vs baseline: 1.4439x; 1.3188x over previous
//
#include <hip/hip_runtime.h>

typedef __bf16 bf16x8 __attribute__((ext_vector_type(8)));
typedef __bf16 bf16x4 __attribute__((ext_vector_type(4)));
typedef float  f32x4  __attribute__((ext_vector_type(4)));

#define BN_EPS 1e-5f

__device__ __forceinline__ float mish_f(float x) {
    float xc = fminf(fmaxf(x, -30.0f), 30.0f);
    float u = __expf(xc);
    float num = u * (u + 2.0f);
    return x * __fdividef(num, num + 2.0f);
}

// ---------------- prep: x fp32 -> bf16 ----------------
__global__ void prep_x_kernel(const float* __restrict__ x, __bf16* __restrict__ xbf, int total4) {
    int i = blockIdx.x * blockDim.x + threadIdx.x;
    if (i >= total4) return;
    float4 v = reinterpret_cast<const float4*>(x)[i];
    bf16x4 o;
    o[0] = (__bf16)v.x; o[1] = (__bf16)v.y; o[2] = (__bf16)v.z; o[3] = (__bf16)v.w;
    *reinterpret_cast<bf16x4*>(xbf + (size_t)i * 4) = o;
}

// ---------------- prep: weights -> B^T bf16 ----------------
// W1T[128][256], W2T[128][128], WeT[128][160] (k 144..159 zeroed), WrT[128][128]
__global__ void prep_w_kernel(const float* __restrict__ W1, const float* __restrict__ W2,
                              const float* __restrict__ We, const float* __restrict__ Wr,
                              __bf16* __restrict__ W1T, __bf16* __restrict__ W2T,
                              __bf16* __restrict__ WeT, __bf16* __restrict__ WrT) {
    int i = blockIdx.x * blockDim.x + threadIdx.x;
    if (i < 128 * 256) {
        int n = i >> 8, k = i & 255;
        W1T[n * 256 + k] = (__bf16)W1[k * 128 + n];
    } else if (i < 128 * 256 + 128 * 128) {
        int j = i - 128 * 256;
        int n = j >> 7, k = j & 127;
        W2T[n * 128 + k] = (__bf16)W2[k * 128 + n];
    } else if (i < 128 * 256 + 128 * 128 + 128 * 160) {
        int j = i - (128 * 256 + 128 * 128);
        int n = j / 160, k = j - n * 160;
        WeT[n * 160 + k] = (k < 144) ? (__bf16)We[k * 128 + n] : (__bf16)0.0f;
    } else if (i < 128 * 256 + 128 * 128 + 128 * 160 + 128 * 128) {
        int j = i - (128 * 256 + 128 * 128 + 128 * 160);
        int n = j >> 7, k = j & 127;
        WrT[n * 128 + k] = (__bf16)Wr[k * 128 + n];
    }
}

// ---------------- counting sort by dst ----------------
__global__ void hist_kernel(const int* __restrict__ eidx, int* __restrict__ count, int E_) {
    int e = blockIdx.x * blockDim.x + threadIdx.x;
    if (e < E_) atomicAdd(&count[eidx[E_ + e]], 1);
}

__global__ __launch_bounds__(1024) void scan_kernel(const int* __restrict__ count,
                                                    int* __restrict__ cursor, int Nn) {
    __shared__ int part[1024];
    const int t = threadIdx.x;
    const int chunk = (Nn + 1023) >> 10;
    const int lo = t * chunk;
    const int hi = min(lo + chunk, Nn);
    int s = 0;
    for (int i = lo; i < hi; ++i) s += count[i];
    part[t] = s;
    __syncthreads();
    for (int off = 1; off < 1024; off <<= 1) {
        int v = (t >= off) ? part[t - off] : 0;
        __syncthreads();
        part[t] += v;
        __syncthreads();
    }
    int run = (t == 0) ? 0 : part[t - 1];
    for (int i = lo; i < hi; ++i) { cursor[i] = run; run += count[i]; }
}

__global__ void scatter_kernel(const int* __restrict__ eidx, int* __restrict__ cursor,
                               int* __restrict__ dstS, int* __restrict__ srcS,
                               int* __restrict__ perm, int E_) {
    int e = blockIdx.x * blockDim.x + threadIdx.x;
    if (e >= E_) return;
    int d = eidx[E_ + e];
    int p = atomicAdd(&cursor[d], 1);
    dstS[p] = d;
    srcS[p] = eidx[e];
    perm[p] = e;
}

// ---------------- main edge kernel ----------------
// Block = 4 waves, all working on the SAME 16 sorted edges per chunk.
// Wave w owns output channels [32w, 32w+32) and holds ALL its B-fragments
// (W1:64 + W2:32 + We:40 = 136 VGPRs) in registers for the whole kernel.
// h1 (GEMM1 output = GEMM2 K-input, all 128 ch) is exchanged via LDS.
// MFMA 16x16x32 layouts:
//   A: lane holds A[m = lane&15][k = quad*8 + j]
//   B: lane holds B[k = quad*8 + j][n = lane&15]   (from B^T rows)
//   C/D: reg r holds D[row = quad*4 + r][col = lane&15]
__global__ __launch_bounds__(256, 2) void edge_kernel(
    const __bf16* __restrict__ xbf,
    const int* __restrict__ dstS, const int* __restrict__ srcS, const int* __restrict__ perm,
    const float* __restrict__ eattr,
    const __bf16* __restrict__ W1T, const float* __restrict__ b1,
    const __bf16* __restrict__ W2T, const float* __restrict__ b2,
    const __bf16* __restrict__ WeT, const float* __restrict__ be,
    float* __restrict__ aggr, int E_, int nchunks)
{
    __shared__ __align__(16) __bf16 h1s[16][136];  // 16 edges x 128 ch (+8 pad)

    const int wid  = threadIdx.x >> 6;
    const int lane = threadIdx.x & 63;
    const int quad = lane >> 4;
    const int l16  = lane & 15;
    const int half = lane >> 5;          // reduction: rows 8h..8h+7
    const int c32  = lane & 31;          // reduction: channel within slice
    const int tsel = (lane >> 4) & 1;    // reduction: which acc tile

    // channel rows for this wave's two 16-col tiles
    const int n0 = (2 * wid) * 16 + l16;
    const int n1 = (2 * wid + 1) * 16 + l16;

    // ---- persistent B fragments (one-time load) ----
    bf16x8 bw1[8][2], bw2[4][2], bwe[5][2];
    #pragma unroll
    for (int kt = 0; kt < 8; ++kt) {
        bw1[kt][0] = *reinterpret_cast<const bf16x8*>(W1T + n0 * 256 + kt * 32 + quad * 8);
        bw1[kt][1] = *reinterpret_cast<const bf16x8*>(W1T + n1 * 256 + kt * 32 + quad * 8);
    }
    #pragma unroll
    for (int kt = 0; kt < 4; ++kt) {
        bw2[kt][0] = *reinterpret_cast<const bf16x8*>(W2T + n0 * 128 + kt * 32 + quad * 8);
        bw2[kt][1] = *reinterpret_cast<const bf16x8*>(W2T + n1 * 128 + kt * 32 + quad * 8);
    }
    #pragma unroll
    for (int kt = 0; kt < 5; ++kt) {
        bwe[kt][0] = *reinterpret_cast<const bf16x8*>(WeT + n0 * 160 + kt * 32 + quad * 8);
        bwe[kt][1] = *reinterpret_cast<const bf16x8*>(WeT + n1 * 160 + kt * 32 + quad * 8);
    }
    const float bb1[2] = { b1[n0], b1[n1] };
    const float bb2[2] = { b2[n0], b2[n1] };
    const float bbe[2] = { be[n0], be[n1] };

    const f32x4 fz4 = {0.f, 0.f, 0.f, 0.f};

    for (int ch = blockIdx.x; ch < nchunks; ch += gridDim.x) {
        const int e0 = ch * 16;
        int em = e0 + l16; if (em > E_ - 1) em = E_ - 1;
        const int src_m = srcS[em];
        const int dst_m = dstS[em];
        const int pm    = perm[em];

        // ---- A frags for GEMM1: cat(x_i, x_j), K=256 ----
        bf16x8 a1[8];
        #pragma unroll
        for (int kt = 0; kt < 4; ++kt)
            a1[kt] = *reinterpret_cast<const bf16x8*>(xbf + (size_t)dst_m * 128 + kt * 32 + quad * 8);
        #pragma unroll
        for (int kt = 4; kt < 8; ++kt)
            a1[kt] = *reinterpret_cast<const bf16x8*>(xbf + (size_t)src_m * 128 + (kt - 4) * 32 + quad * 8);

        // ---- A frags for GEMMe: cat(eattr, x_j, pad), K=160 (144 real) ----
        bf16x8 ae[5];
        if (quad < 2) {
            const float4* p = reinterpret_cast<const float4*>(eattr + (size_t)pm * 16 + quad * 8);
            float4 v0 = p[0], v1 = p[1];
            ae[0][0] = (__bf16)v0.x; ae[0][1] = (__bf16)v0.y; ae[0][2] = (__bf16)v0.z; ae[0][3] = (__bf16)v0.w;
            ae[0][4] = (__bf16)v1.x; ae[0][5] = (__bf16)v1.y; ae[0][6] = (__bf16)v1.z; ae[0][7] = (__bf16)v1.w;
        } else {
            ae[0] = *reinterpret_cast<const bf16x8*>(xbf + (size_t)src_m * 128 + (quad - 2) * 8);
        }
        #pragma unroll
        for (int kt = 1; kt < 4; ++kt)
            ae[kt] = *reinterpret_cast<const bf16x8*>(xbf + (size_t)src_m * 128 + kt * 32 + quad * 8 - 16);
        if (quad < 2) {
            ae[4] = *reinterpret_cast<const bf16x8*>(xbf + (size_t)src_m * 128 + 112 + quad * 8);
        } else {
            #pragma unroll
            for (int j = 0; j < 8; ++j) ae[4][j] = (__bf16)0.0f;  // B is zero-padded there too
        }

        // ---- GEMM1 ----
        f32x4 acc1[2] = {fz4, fz4};
        #pragma unroll
        for (int kt = 0; kt < 8; ++kt) {
            acc1[0] = __builtin_amdgcn_mfma_f32_16x16x32_bf16(a1[kt], bw1[kt][0], acc1[0], 0, 0, 0);
            acc1[1] = __builtin_amdgcn_mfma_f32_16x16x32_bf16(a1[kt], bw1[kt][1], acc1[1], 0, 0, 0);
        }
        // mish -> LDS (this wave's 32 channels)
        #pragma unroll
        for (int t = 0; t < 2; ++t) {
            #pragma unroll
            for (int r = 0; r < 4; ++r) {
                float v = mish_f(acc1[t][r] + bb1[t]);
                h1s[quad * 4 + r][(2 * wid + t) * 16 + l16] = (__bf16)v;
            }
        }
        __syncthreads();

        // ---- GEMMe ----
        f32x4 acce[2] = {fz4, fz4};
        #pragma unroll
        for (int kt = 0; kt < 5; ++kt) {
            acce[0] = __builtin_amdgcn_mfma_f32_16x16x32_bf16(ae[kt], bwe[kt][0], acce[0], 0, 0, 0);
            acce[1] = __builtin_amdgcn_mfma_f32_16x16x32_bf16(ae[kt], bwe[kt][1], acce[1], 0, 0, 0);
        }

        // ---- GEMM2 (A from shared h1) ----
        f32x4 acc2[2] = {fz4, fz4};
        #pragma unroll
        for (int kt = 0; kt < 4; ++kt) {
            bf16x8 a = *reinterpret_cast<const bf16x8*>(&h1s[l16][kt * 32 + quad * 8]);
            acc2[0] = __builtin_amdgcn_mfma_f32_16x16x32_bf16(a, bw2[kt][0], acc2[0], 0, 0, 0);
            acc2[1] = __builtin_amdgcn_mfma_f32_16x16x32_bf16(a, bw2[kt][1], acc2[1], 0, 0, 0);
        }
        __syncthreads();  // h1s consumed; safe to overwrite next chunk

        // ---- msg in C-layout registers ----
        float m0[4], m1[4];
        #pragma unroll
        for (int r = 0; r < 4; ++r) {
            m0[r] = (acc2[0][r] + bb2[0]) * mish_f(acce[0][r] + bbe[0]);
            m1[r] = (acc2[1][r] + bb2[1]) * mish_f(acce[1][r] + bbe[1]);
        }

        // ---- shuffle-based segment reduction over sorted rows ----
        // half h handles rows 8h..8h+7; lane channel = 32*wid + c32
        float racc = 0.f; int curd = -1;
        #pragma unroll
        for (int i = 0; i < 8; ++i) {
            int row  = 8 * half + i;
            int srcL = (row >> 2) * 16 + (c32 & 15);
            float v0 = __shfl(m0[i & 3], srcL);
            float v1 = __shfl(m1[i & 3], srcL);
            float v  = tsel ? v1 : v0;
            if (e0 + row >= E_) v = 0.f;
            int d = __shfl(dst_m, row);
            if (i == 0) { curd = d; racc = v; }
            else if (d != curd) {
                atomicAdd(aggr + (size_t)curd * 128 + 32 * wid + c32, racc);
                curd = d; racc = v;
            } else racc += v;
        }
        atomicAdd(aggr + (size_t)curd * 128 + 32 * wid + c32, racc);
    }
}

// ---------------- node kernel (MFMA): out = aggr + x@Wroot + bias; BN partials ----------------
__global__ __launch_bounds__(256) void node_kernel(
    const __bf16* __restrict__ xbf, const __bf16* __restrict__ WrT,
    const float* __restrict__ bias, float* __restrict__ out,
    float* __restrict__ stats, int N_)
{
    __shared__ float lsum[128], lsq[128];
    const int wid  = threadIdx.x >> 6;
    const int lane = threadIdx.x & 63;
    const int quad = lane >> 4;
    const int l16  = lane & 15;
    const int n0   = (blockIdx.x * 4 + wid) * 16;

    if (threadIdx.x < 128) { lsum[threadIdx.x] = 0.f; lsq[threadIdx.x] = 0.f; }
    __syncthreads();

    int nm = n0 + l16; if (nm > N_ - 1) nm = N_ - 1;

    const f32x4 fz4 = {0.f, 0.f, 0.f, 0.f};
    f32x4 acc[8];
    #pragma unroll
    for (int nt = 0; nt < 8; ++nt) acc[nt] = fz4;
    #pragma unroll
    for (int kt = 0; kt < 4; ++kt) {
        const int gk = kt * 32 + quad * 8;
        bf16x8 a = *reinterpret_cast<const bf16x8*>(xbf + (size_t)nm * 128 + gk);
        #pragma unroll
        for (int nt = 0; nt < 8; ++nt) {
            bf16x8 b = *reinterpret_cast<const bf16x8*>(WrT + (nt * 16 + l16) * 128 + gk);
            acc[nt] = __builtin_amdgcn_mfma_f32_16x16x32_bf16(a, b, acc[nt], 0, 0, 0);
        }
    }

    #pragma unroll
    for (int nt = 0; nt < 8; ++nt) {
        const int c = nt * 16 + l16;
        float bc = bias[c];
        float ps = 0.f, pq = 0.f;
        #pragma unroll
        for (int r = 0; r < 4; ++r) {
            int n = n0 + quad * 4 + r;
            if (n < N_) {
                size_t o = (size_t)n * 128 + c;
                float pre = out[o] + acc[nt][r] + bc;
                out[o] = pre;
                ps += pre; pq += pre * pre;
            }
        }
        atomicAdd(&lsum[c], ps);
        atomicAdd(&lsq[c], pq);
    }
    __syncthreads();
    if (threadIdx.x < 128) {
        atomicAdd(&stats[threadIdx.x],       lsum[threadIdx.x]);
        atomicAdd(&stats[128 + threadIdx.x], lsq[threadIdx.x]);
    }
}

// ---------------- BN finalize ----------------
__global__ void bn_kernel(float* __restrict__ out, const float* __restrict__ stats,
                          const float* __restrict__ gamma, const float* __restrict__ beta,
                          float invN, int total4)
{
    int i = blockIdx.x * blockDim.x + threadIdx.x;
    if (i >= total4) return;
    int c0 = (i & 31) * 4;
    float4 v = reinterpret_cast<float4*>(out)[i];
    float o[4] = {v.x, v.y, v.z, v.w};
    #pragma unroll
    for (int j = 0; j < 4; ++j) {
        int c = c0 + j;
        float mean  = stats[c] * invN;
        float var   = stats[128 + c] * invN - mean * mean;
        float scale = gamma[c] * rsqrtf(var + BN_EPS);
        o[j] = (o[j] - mean) * scale + beta[c];
    }
    v.x = o[0]; v.y = o[1]; v.z = o[2]; v.w = o[3];
    reinterpret_cast<float4*>(out)[i] = v;
}

extern "C" void kernel_launch(void* const* d_in, const int* in_sizes, int n_in,
                              void* d_out, int out_size, void* d_ws, size_t ws_size,
                              hipStream_t stream)
{
    const float* x     = (const float*)d_in[0];
    const int*   eidx  = (const int*)d_in[1];
    const float* eattr = (const float*)d_in[2];
    const float* W1    = (const float*)d_in[3];
    const float* b1    = (const float*)d_in[4];
    const float* W2    = (const float*)d_in[5];
    const float* b2    = (const float*)d_in[6];
    const float* We    = (const float*)d_in[7];
    const float* be    = (const float*)d_in[8];
    const float* Wroot = (const float*)d_in[9];
    const float* bias  = (const float*)d_in[10];
    const float* gamma = (const float*)d_in[11];
    const float* beta  = (const float*)d_in[12];

    const int N_ = in_sizes[0] / 128;
    const int E_ = in_sizes[1] / 2;

    char* ws = (char*)d_ws;
    size_t off = 0;
    __bf16* xbf = (__bf16*)(ws + off); off += (size_t)N_ * 128 * 2;
    __bf16* W1T = (__bf16*)(ws + off); off += 128 * 256 * 2;
    __bf16* W2T = (__bf16*)(ws + off); off += 128 * 128 * 2;
    __bf16* WeT = (__bf16*)(ws + off); off += 128 * 160 * 2;
    __bf16* WrT = (__bf16*)(ws + off); off += 128 * 128 * 2;
    float* stats = (float*)(ws + off); off += 256 * 4;
    off = (off + 15) & ~(size_t)15;
    int* count  = (int*)(ws + off); off += (size_t)N_ * 4;
    int* cursor = (int*)(ws + off); off += (size_t)N_ * 4;
    int* dstS   = (int*)(ws + off); off += (size_t)E_ * 4;
    int* srcS   = (int*)(ws + off); off += (size_t)E_ * 4;
    int* perm   = (int*)(ws + off); off += (size_t)E_ * 4;

    float* out = (float*)d_out;

    hipMemsetAsync(out, 0, (size_t)out_size * sizeof(float), stream);
    hipMemsetAsync(stats, 0, 256 * sizeof(float), stream);
    hipMemsetAsync(count, 0, (size_t)N_ * sizeof(int), stream);

    int total4 = N_ * 32;
    prep_x_kernel<<<(total4 + 255) / 256, 256, 0, stream>>>(x, xbf, total4);
    int wtot = 128 * 256 + 128 * 128 + 128 * 160 + 128 * 128;
    prep_w_kernel<<<(wtot + 255) / 256, 256, 0, stream>>>(W1, W2, We, Wroot, W1T, W2T, WeT, WrT);

    hist_kernel<<<(E_ + 255) / 256, 256, 0, stream>>>(eidx, count, E_);
    scan_kernel<<<1, 1024, 0, stream>>>(count, cursor, N_);
    scatter_kernel<<<(E_ + 255) / 256, 256, 0, stream>>>(eidx, cursor, dstS, srcS, perm, E_);

    int nchunks = (E_ + 15) / 16;
    edge_kernel<<<2048, 256, 0, stream>>>(xbf, dstS, srcS, perm, eattr,
                                          W1T, b1, W2T, b2, WeT, be, out, E_, nchunks);

    int ntiles = (N_ + 15) / 16;
    node_kernel<<<(ntiles + 3) / 4, 256, 0, stream>>>(xbf, WrT, bias, out, stats, N_);

    bn_kernel<<<(total4 + 255) / 256, 256, 0, stream>>>(out, stats, gamma, beta, 1.0f / (float)N_, total4);
}

// Round 4
// 740.373 us; speedup vs baseline: 1.6384x; 1.1347x over previous
//
#include <hip/hip_runtime.h>

typedef __bf16 bf16x8 __attribute__((ext_vector_type(8)));
typedef __bf16 bf16x4 __attribute__((ext_vector_type(4)));
typedef float  f32x4  __attribute__((ext_vector_type(4)));

#define BN_EPS 1e-5f

__device__ __forceinline__ float mish_f(float x) {
    float xc = fminf(fmaxf(x, -30.0f), 30.0f);
    float u = __expf(xc);
    float num = u * (u + 2.0f);
    return x * __fdividef(num, num + 2.0f);
}

__device__ __forceinline__ bf16x8 as_bf16x8(f32x4 v) {
    union { f32x4 f; bf16x8 b; } u; u.f = v; return u.b;
}

// ---------------- prep: x fp32 -> bf16 ----------------
__global__ void prep_x_kernel(const float* __restrict__ x, __bf16* __restrict__ xbf, int total4) {
    int i = blockIdx.x * blockDim.x + threadIdx.x;
    if (i >= total4) return;
    float4 v = reinterpret_cast<const float4*>(x)[i];
    bf16x4 o;
    o[0] = (__bf16)v.x; o[1] = (__bf16)v.y; o[2] = (__bf16)v.z; o[3] = (__bf16)v.w;
    *reinterpret_cast<bf16x4*>(xbf + (size_t)i * 4) = o;
}

// ---------------- prep: weights -> B^T bf16 ----------------
// W1T[128][256]
// W2T[128][128]
// WeT[128][160] with REORDERED K: k<128 -> We row k+16 (x_j part),
//                 128<=k<144 -> We row k-128 (eattr part), k>=144 -> 0
// WrT[128][128]
__global__ void prep_w_kernel(const float* __restrict__ W1, const float* __restrict__ W2,
                              const float* __restrict__ We, const float* __restrict__ Wr,
                              __bf16* __restrict__ W1T, __bf16* __restrict__ W2T,
                              __bf16* __restrict__ WeT, __bf16* __restrict__ WrT) {
    int i = blockIdx.x * blockDim.x + threadIdx.x;
    if (i < 128 * 256) {
        int n = i >> 8, k = i & 255;
        W1T[n * 256 + k] = (__bf16)W1[k * 128 + n];
    } else if (i < 128 * 256 + 128 * 128) {
        int j = i - 128 * 256;
        int n = j >> 7, k = j & 127;
        W2T[n * 128 + k] = (__bf16)W2[k * 128 + n];
    } else if (i < 128 * 256 + 128 * 128 + 128 * 160) {
        int j = i - (128 * 256 + 128 * 128);
        int n = j / 160, k = j - n * 160;
        float v = 0.0f;
        if (k < 128) v = We[(k + 16) * 128 + n];
        else if (k < 144) v = We[(k - 128) * 128 + n];
        WeT[n * 160 + k] = (__bf16)v;
    } else if (i < 128 * 256 + 128 * 128 + 128 * 160 + 128 * 128) {
        int j = i - (128 * 256 + 128 * 128 + 128 * 160);
        int n = j >> 7, k = j & 127;
        WrT[n * 128 + k] = (__bf16)Wr[k * 128 + n];
    }
}

// ---------------- counting sort by dst ----------------
__global__ void hist_kernel(const int* __restrict__ eidx, int* __restrict__ count, int E_) {
    int e = blockIdx.x * blockDim.x + threadIdx.x;
    if (e < E_) atomicAdd(&count[eidx[E_ + e]], 1);
}

__global__ __launch_bounds__(1024) void scan_kernel(const int* __restrict__ count,
                                                    int* __restrict__ cursor, int Nn) {
    __shared__ int part[1024];
    const int t = threadIdx.x;
    const int chunk = (Nn + 1023) >> 10;
    const int lo = t * chunk;
    const int hi = min(lo + chunk, Nn);
    int s = 0;
    for (int i = lo; i < hi; ++i) s += count[i];
    part[t] = s;
    __syncthreads();
    for (int off = 1; off < 1024; off <<= 1) {
        int v = (t >= off) ? part[t - off] : 0;
        __syncthreads();
        part[t] += v;
        __syncthreads();
    }
    int run = (t == 0) ? 0 : part[t - 1];
    for (int i = lo; i < hi; ++i) { cursor[i] = run; run += count[i]; }
}

__global__ void scatter_kernel(const int* __restrict__ eidx, int* __restrict__ cursor,
                               int* __restrict__ dstS, int* __restrict__ srcS,
                               int* __restrict__ perm, int E_) {
    int e = blockIdx.x * blockDim.x + threadIdx.x;
    if (e >= E_) return;
    int d = eidx[E_ + e];
    int p = atomicAdd(&cursor[d], 1);
    dstS[p] = d;
    srcS[p] = eidx[e];
    perm[p] = e;
}

// ---------------- main edge kernel ----------------
// Block = 4 waves on the SAME 16 sorted edges per chunk. Wave w owns output
// channels [32w,32w+32) and keeps its 136 VGPRs of B-fragments resident
// (asm barrier pins them — compiler otherwise rematerializes the loads).
// GEMMe reuses GEMM1's x_j A-frags via the reordered WeT (see prep).
// MFMA 16x16x32: A[m=lane&15][k=quad*8+j]; B from B^T rows; C/D r -> row quad*4+r.
__global__ __launch_bounds__(256, 2) void edge_kernel(
    const __bf16* __restrict__ xbf,
    const int* __restrict__ dstS, const int* __restrict__ srcS, const int* __restrict__ perm,
    const float* __restrict__ eattr,
    const __bf16* __restrict__ W1T, const float* __restrict__ b1,
    const __bf16* __restrict__ W2T, const float* __restrict__ b2,
    const __bf16* __restrict__ WeT, const float* __restrict__ be,
    float* __restrict__ aggr, int E_, int nchunks)
{
    __shared__ __align__(16) __bf16 h1s[16][136];

    const int wid  = threadIdx.x >> 6;
    const int lane = threadIdx.x & 63;
    const int quad = lane >> 4;
    const int l16  = lane & 15;
    const int half = lane >> 5;
    const int c32  = lane & 31;
    const int tsel = (lane >> 4) & 1;

    const int n0 = (2 * wid) * 16 + l16;
    const int n1 = (2 * wid + 1) * 16 + l16;

    // ---- persistent B fragments (pinned in VGPRs) ----
    f32x4 bw1[8][2], bw2[4][2], bwe[5][2];
    #pragma unroll
    for (int kt = 0; kt < 8; ++kt) {
        bw1[kt][0] = *reinterpret_cast<const f32x4*>(W1T + n0 * 256 + kt * 32 + quad * 8);
        bw1[kt][1] = *reinterpret_cast<const f32x4*>(W1T + n1 * 256 + kt * 32 + quad * 8);
    }
    #pragma unroll
    for (int kt = 0; kt < 4; ++kt) {
        bw2[kt][0] = *reinterpret_cast<const f32x4*>(W2T + n0 * 128 + kt * 32 + quad * 8);
        bw2[kt][1] = *reinterpret_cast<const f32x4*>(W2T + n1 * 128 + kt * 32 + quad * 8);
    }
    #pragma unroll
    for (int kt = 0; kt < 5; ++kt) {
        bwe[kt][0] = *reinterpret_cast<const f32x4*>(WeT + n0 * 160 + kt * 32 + quad * 8);
        bwe[kt][1] = *reinterpret_cast<const f32x4*>(WeT + n1 * 160 + kt * 32 + quad * 8);
    }
    #pragma unroll
    for (int kt = 0; kt < 8; ++kt) {
        asm volatile("" : "+v"(bw1[kt][0]), "+v"(bw1[kt][1]));
    }
    #pragma unroll
    for (int kt = 0; kt < 4; ++kt) {
        asm volatile("" : "+v"(bw2[kt][0]), "+v"(bw2[kt][1]));
    }
    #pragma unroll
    for (int kt = 0; kt < 5; ++kt) {
        asm volatile("" : "+v"(bwe[kt][0]), "+v"(bwe[kt][1]));
    }
    const float bb1[2] = { b1[n0], b1[n1] };
    const float bb2[2] = { b2[n0], b2[n1] };
    const float bbe[2] = { be[n0], be[n1] };

    const f32x4 fz4 = {0.f, 0.f, 0.f, 0.f};

    for (int ch = blockIdx.x; ch < nchunks; ch += gridDim.x) {
        const int e0 = ch * 16;
        int em = e0 + l16; if (em > E_ - 1) em = E_ - 1;
        const int src_m = srcS[em];
        const int dst_m = dstS[em];
        const int pm    = perm[em];

        // ---- A frags: a1 = cat(x_i, x_j), K=256; ae_x = [eattr|pad], K tail ----
        bf16x8 a1[8];
        #pragma unroll
        for (int kt = 0; kt < 4; ++kt)
            a1[kt] = *reinterpret_cast<const bf16x8*>(xbf + (size_t)dst_m * 128 + kt * 32 + quad * 8);
        #pragma unroll
        for (int kt = 4; kt < 8; ++kt)
            a1[kt] = *reinterpret_cast<const bf16x8*>(xbf + (size_t)src_m * 128 + (kt - 4) * 32 + quad * 8);

        bf16x8 ae_x;
        #pragma unroll
        for (int j = 0; j < 8; ++j) ae_x[j] = (__bf16)0.0f;
        if (quad < 2) {
            const float4* p = reinterpret_cast<const float4*>(eattr + (size_t)pm * 16 + quad * 8);
            float4 v0 = p[0], v1 = p[1];
            ae_x[0] = (__bf16)v0.x; ae_x[1] = (__bf16)v0.y; ae_x[2] = (__bf16)v0.z; ae_x[3] = (__bf16)v0.w;
            ae_x[4] = (__bf16)v1.x; ae_x[5] = (__bf16)v1.y; ae_x[6] = (__bf16)v1.z; ae_x[7] = (__bf16)v1.w;
        }

        // ---- GEMM1 ----
        f32x4 acc1[2] = {fz4, fz4};
        #pragma unroll
        for (int kt = 0; kt < 8; ++kt) {
            acc1[0] = __builtin_amdgcn_mfma_f32_16x16x32_bf16(a1[kt], as_bf16x8(bw1[kt][0]), acc1[0], 0, 0, 0);
            acc1[1] = __builtin_amdgcn_mfma_f32_16x16x32_bf16(a1[kt], as_bf16x8(bw1[kt][1]), acc1[1], 0, 0, 0);
        }
        #pragma unroll
        for (int t = 0; t < 2; ++t) {
            #pragma unroll
            for (int r = 0; r < 4; ++r) {
                float v = mish_f(acc1[t][r] + bb1[t]);
                h1s[quad * 4 + r][(2 * wid + t) * 16 + l16] = (__bf16)v;
            }
        }
        __syncthreads();

        // ---- GEMMe: A kt=0..3 reuse a1[4..7] (x_j), kt=4 is [eattr|pad] ----
        f32x4 acce[2] = {fz4, fz4};
        #pragma unroll
        for (int kt = 0; kt < 4; ++kt) {
            acce[0] = __builtin_amdgcn_mfma_f32_16x16x32_bf16(a1[kt + 4], as_bf16x8(bwe[kt][0]), acce[0], 0, 0, 0);
            acce[1] = __builtin_amdgcn_mfma_f32_16x16x32_bf16(a1[kt + 4], as_bf16x8(bwe[kt][1]), acce[1], 0, 0, 0);
        }
        acce[0] = __builtin_amdgcn_mfma_f32_16x16x32_bf16(ae_x, as_bf16x8(bwe[4][0]), acce[0], 0, 0, 0);
        acce[1] = __builtin_amdgcn_mfma_f32_16x16x32_bf16(ae_x, as_bf16x8(bwe[4][1]), acce[1], 0, 0, 0);

        // ---- GEMM2 (A from shared h1) ----
        f32x4 acc2[2] = {fz4, fz4};
        #pragma unroll
        for (int kt = 0; kt < 4; ++kt) {
            bf16x8 a = *reinterpret_cast<const bf16x8*>(&h1s[l16][kt * 32 + quad * 8]);
            acc2[0] = __builtin_amdgcn_mfma_f32_16x16x32_bf16(a, as_bf16x8(bw2[kt][0]), acc2[0], 0, 0, 0);
            acc2[1] = __builtin_amdgcn_mfma_f32_16x16x32_bf16(a, as_bf16x8(bw2[kt][1]), acc2[1], 0, 0, 0);
        }
        __syncthreads();

        // ---- msg ----
        float m0[4], m1[4];
        #pragma unroll
        for (int r = 0; r < 4; ++r) {
            m0[r] = (acc2[0][r] + bb2[0]) * mish_f(acce[0][r] + bbe[0]);
            m1[r] = (acc2[1][r] + bb2[1]) * mish_f(acce[1][r] + bbe[1]);
        }

        // ---- shuffle segment reduction over sorted rows ----
        float racc = 0.f; int curd = -1;
        #pragma unroll
        for (int i = 0; i < 8; ++i) {
            int row  = 8 * half + i;
            int srcL = (row >> 2) * 16 + (c32 & 15);
            float v0 = __shfl(m0[i & 3], srcL);
            float v1 = __shfl(m1[i & 3], srcL);
            float v  = tsel ? v1 : v0;
            if (e0 + row >= E_) v = 0.f;
            int d = __shfl(dst_m, row);
            if (i == 0) { curd = d; racc = v; }
            else if (d != curd) {
                atomicAdd(aggr + (size_t)curd * 128 + 32 * wid + c32, racc);
                curd = d; racc = v;
            } else racc += v;
        }
        atomicAdd(aggr + (size_t)curd * 128 + 32 * wid + c32, racc);
    }
}

// ---------------- node kernel: 64 nodes/block; out = aggr + x@Wroot + bias; BN partials ----------------
__global__ __launch_bounds__(256, 2) void node_kernel(
    const __bf16* __restrict__ xbf, const __bf16* __restrict__ WrT,
    const float* __restrict__ bias, float* __restrict__ out,
    float* __restrict__ stats, int N_)
{
    __shared__ float accS[4][16][132];   // 33.8 KB, row stride 132 (528B, 16B-aligned)
    __shared__ float redS[8][32][8];     // 8 KB

    const int wid  = threadIdx.x >> 6;
    const int lane = threadIdx.x & 63;
    const int quad = lane >> 4;
    const int l16  = lane & 15;
    const int n0   = blockIdx.x * 64;

    int nm = n0 + wid * 16 + l16; if (nm > N_ - 1) nm = N_ - 1;

    const f32x4 fz4 = {0.f, 0.f, 0.f, 0.f};
    f32x4 acc[8];
    #pragma unroll
    for (int nt = 0; nt < 8; ++nt) acc[nt] = fz4;
    #pragma unroll
    for (int kt = 0; kt < 4; ++kt) {
        const int gk = kt * 32 + quad * 8;
        bf16x8 a = *reinterpret_cast<const bf16x8*>(xbf + (size_t)nm * 128 + gk);
        #pragma unroll
        for (int nt = 0; nt < 8; ++nt) {
            bf16x8 b = *reinterpret_cast<const bf16x8*>(WrT + (nt * 16 + l16) * 128 + gk);
            acc[nt] = __builtin_amdgcn_mfma_f32_16x16x32_bf16(a, b, acc[nt], 0, 0, 0);
        }
    }
    #pragma unroll
    for (int nt = 0; nt < 8; ++nt) {
        #pragma unroll
        for (int r = 0; r < 4; ++r)
            accS[wid][quad * 4 + r][nt * 16 + l16] = acc[nt][r];
    }
    __syncthreads();

    // RMW out with float4, accumulate per-channel partials
    const int c4  = threadIdx.x & 31;   // which float4 of 128 channels
    const int grp = threadIdx.x >> 5;   // 8 row-groups
    float4 bb = reinterpret_cast<const float4*>(bias)[c4];
    float ps[4] = {0.f, 0.f, 0.f, 0.f}, pq[4] = {0.f, 0.f, 0.f, 0.f};
    #pragma unroll
    for (int i = 0; i < 8; ++i) {
        int row = grp * 8 + i;
        int n = n0 + row;
        if (n < N_) {
            float4 v = reinterpret_cast<float4*>(out)[(size_t)n * 32 + c4];
            f32x4 ac = *reinterpret_cast<f32x4*>(&accS[row >> 4][row & 15][c4 * 4]);
            v.x += ac[0] + bb.x; v.y += ac[1] + bb.y; v.z += ac[2] + bb.z; v.w += ac[3] + bb.w;
            reinterpret_cast<float4*>(out)[(size_t)n * 32 + c4] = v;
            ps[0] += v.x; ps[1] += v.y; ps[2] += v.z; ps[3] += v.w;
            pq[0] += v.x * v.x; pq[1] += v.y * v.y; pq[2] += v.z * v.z; pq[3] += v.w * v.w;
        }
    }
    #pragma unroll
    for (int j = 0; j < 4; ++j) { redS[grp][c4][j] = ps[j]; redS[grp][c4][4 + j] = pq[j]; }
    __syncthreads();

    // 256 threads cover 32 c4-groups x 8 slots
    {
        const int cc = threadIdx.x & 31, jj = threadIdx.x >> 5;
        float s = 0.f;
        #pragma unroll
        for (int k = 0; k < 8; ++k) s += redS[k][cc][jj];
        if (jj < 4) atomicAdd(&stats[cc * 4 + jj], s);
        else        atomicAdd(&stats[128 + cc * 4 + (jj - 4)], s);
    }
}

// ---------------- BN finalize ----------------
__global__ void bn_kernel(float* __restrict__ out, const float* __restrict__ stats,
                          const float* __restrict__ gamma, const float* __restrict__ beta,
                          float invN, int total4)
{
    int i = blockIdx.x * blockDim.x + threadIdx.x;
    if (i >= total4) return;
    int c0 = (i & 31) * 4;
    float4 v = reinterpret_cast<float4*>(out)[i];
    float o[4] = {v.x, v.y, v.z, v.w};
    #pragma unroll
    for (int j = 0; j < 4; ++j) {
        int c = c0 + j;
        float mean  = stats[c] * invN;
        float var   = stats[128 + c] * invN - mean * mean;
        float scale = gamma[c] * rsqrtf(var + BN_EPS);
        o[j] = (o[j] - mean) * scale + beta[c];
    }
    v.x = o[0]; v.y = o[1]; v.z = o[2]; v.w = o[3];
    reinterpret_cast<float4*>(out)[i] = v;
}

extern "C" void kernel_launch(void* const* d_in, const int* in_sizes, int n_in,
                              void* d_out, int out_size, void* d_ws, size_t ws_size,
                              hipStream_t stream)
{
    const float* x     = (const float*)d_in[0];
    const int*   eidx  = (const int*)d_in[1];
    const float* eattr = (const float*)d_in[2];
    const float* W1    = (const float*)d_in[3];
    const float* b1    = (const float*)d_in[4];
    const float* W2    = (const float*)d_in[5];
    const float* b2    = (const float*)d_in[6];
    const float* We    = (const float*)d_in[7];
    const float* be    = (const float*)d_in[8];
    const float* Wroot = (const float*)d_in[9];
    const float* bias  = (const float*)d_in[10];
    const float* gamma = (const float*)d_in[11];
    const float* beta  = (const float*)d_in[12];

    const int N_ = in_sizes[0] / 128;
    const int E_ = in_sizes[1] / 2;

    char* ws = (char*)d_ws;
    size_t off = 0;
    __bf16* xbf = (__bf16*)(ws + off); off += (size_t)N_ * 128 * 2;
    __bf16* W1T = (__bf16*)(ws + off); off += 128 * 256 * 2;
    __bf16* W2T = (__bf16*)(ws + off); off += 128 * 128 * 2;
    __bf16* WeT = (__bf16*)(ws + off); off += 128 * 160 * 2;
    __bf16* WrT = (__bf16*)(ws + off); off += 128 * 128 * 2;
    float* stats = (float*)(ws + off); off += 256 * 4;
    off = (off + 15) & ~(size_t)15;
    int* count  = (int*)(ws + off); off += (size_t)N_ * 4;
    int* cursor = (int*)(ws + off); off += (size_t)N_ * 4;
    int* dstS   = (int*)(ws + off); off += (size_t)E_ * 4;
    int* srcS   = (int*)(ws + off); off += (size_t)E_ * 4;
    int* perm   = (int*)(ws + off); off += (size_t)E_ * 4;

    float* out = (float*)d_out;

    hipMemsetAsync(out, 0, (size_t)out_size * sizeof(float), stream);
    hipMemsetAsync(stats, 0, 256 * sizeof(float), stream);
    hipMemsetAsync(count, 0, (size_t)N_ * sizeof(int), stream);

    int total4 = N_ * 32;
    prep_x_kernel<<<(total4 + 255) / 256, 256, 0, stream>>>(x, xbf, total4);
    int wtot = 128 * 256 + 128 * 128 + 128 * 160 + 128 * 128;
    prep_w_kernel<<<(wtot + 255) / 256, 256, 0, stream>>>(W1, W2, We, Wroot, W1T, W2T, WeT, WrT);

    hist_kernel<<<(E_ + 255) / 256, 256, 0, stream>>>(eidx, count, E_);
    scan_kernel<<<1, 1024, 0, stream>>>(count, cursor, N_);
    scatter_kernel<<<(E_ + 255) / 256, 256, 0, stream>>>(eidx, cursor, dstS, srcS, perm, E_);

    int nchunks = (E_ + 15) / 16;
    edge_kernel<<<2048, 256, 0, stream>>>(xbf, dstS, srcS, perm, eattr,
                                          W1T, b1, W2T, b2, WeT, be, out, E_, nchunks);

    node_kernel<<<(N_ + 63) / 64, 256, 0, stream>>>(xbf, WrT, bias, out, stats, N_);

    bn_kernel<<<(total4 + 255) / 256, 256, 0, stream>>>(out, stats, gamma, beta, 1.0f / (float)N_, total4);
}

// Round 5
// 633.949 us; speedup vs baseline: 1.9134x; 1.1679x over previous
//
#include <hip/hip_runtime.h>

typedef __bf16 bf16x8 __attribute__((ext_vector_type(8)));
typedef __bf16 bf16x4 __attribute__((ext_vector_type(4)));
typedef float  f32x4  __attribute__((ext_vector_type(4)));

#define BN_EPS 1e-5f

__device__ __forceinline__ float mish_f(float x) {
    float xc = fminf(fmaxf(x, -30.0f), 30.0f);
    float u = __expf(xc);
    float num = u * (u + 2.0f);
    return x * __fdividef(num, num + 2.0f);
}

// ---------------- prep: weights -> fused B^T bf16 ----------------
// WcatT[512][128]: n<128 -> W1 rows 0..127 (x_i) | n<256 -> W1 rows 128..255 (x_j)
//                  n<384 -> We rows 16..143 (x_j) | n<512 -> Wroot
// W2T[128][128]; WeeT[128][32] (k<16 -> We rows 0..15 (eattr), else 0)
__global__ void prep_w_kernel(const float* __restrict__ W1, const float* __restrict__ W2,
                              const float* __restrict__ We, const float* __restrict__ Wr,
                              __bf16* __restrict__ WcatT, __bf16* __restrict__ W2T,
                              __bf16* __restrict__ WeeT) {
    int i = blockIdx.x * blockDim.x + threadIdx.x;
    if (i < 512 * 128) {
        int n = i >> 7, k = i & 127;
        float v;
        if (n < 128)      v = W1[k * 128 + n];
        else if (n < 256) v = W1[(128 + k) * 128 + (n - 128)];
        else if (n < 384) v = We[(16 + k) * 128 + (n - 256)];
        else              v = Wr[k * 128 + (n - 384)];
        WcatT[(size_t)n * 128 + k] = (__bf16)v;
    } else if (i < 512 * 128 + 128 * 128) {
        int j = i - 512 * 128;
        int n = j >> 7, k = j & 127;
        W2T[n * 128 + k] = (__bf16)W2[k * 128 + n];
    } else if (i < 512 * 128 + 128 * 128 + 128 * 32) {
        int j = i - (512 * 128 + 128 * 128);
        int n = j >> 5, k = j & 31;
        WeeT[n * 32 + k] = (k < 16) ? (__bf16)We[k * 128 + n] : (__bf16)0.0f;
    }
}

// ---------------- precompute P[n][512] = x[n] @ [W1a|W1b|We_x|Wroot] (bf16) ----------------
__global__ __launch_bounds__(256) void precompute_kernel(
    const float* __restrict__ x, const __bf16* __restrict__ WcatT,
    __bf16* __restrict__ P, int N_)
{
    const int wid  = threadIdx.x >> 6;
    const int lane = threadIdx.x & 63;
    const int quad = lane >> 4;
    const int l16  = lane & 15;

    int rl = blockIdx.x * 64 + wid * 16 + l16;
    if (rl > N_ - 1) rl = N_ - 1;

    // A frags: 16 rows x K=128
    bf16x8 a[4];
    #pragma unroll
    for (int kt = 0; kt < 4; ++kt) {
        const float4* p = reinterpret_cast<const float4*>(x + (size_t)rl * 128 + kt * 32 + quad * 8);
        float4 v0 = p[0], v1 = p[1];
        a[kt][0] = (__bf16)v0.x; a[kt][1] = (__bf16)v0.y; a[kt][2] = (__bf16)v0.z; a[kt][3] = (__bf16)v0.w;
        a[kt][4] = (__bf16)v1.x; a[kt][5] = (__bf16)v1.y; a[kt][6] = (__bf16)v1.z; a[kt][7] = (__bf16)v1.w;
    }

    const f32x4 fz4 = {0.f, 0.f, 0.f, 0.f};
    #pragma unroll
    for (int g = 0; g < 4; ++g) {
        f32x4 acc[8];
        #pragma unroll
        for (int nt = 0; nt < 8; ++nt) acc[nt] = fz4;
        #pragma unroll
        for (int kt = 0; kt < 4; ++kt) {
            #pragma unroll
            for (int nt = 0; nt < 8; ++nt) {
                bf16x8 b = *reinterpret_cast<const bf16x8*>(
                    WcatT + (size_t)((g * 8 + nt) * 16 + l16) * 128 + kt * 32 + quad * 8);
                acc[nt] = __builtin_amdgcn_mfma_f32_16x16x32_bf16(a[kt], b, acc[nt], 0, 0, 0);
            }
        }
        #pragma unroll
        for (int nt = 0; nt < 8; ++nt) {
            #pragma unroll
            for (int r = 0; r < 4; ++r) {
                int row = blockIdx.x * 64 + wid * 16 + quad * 4 + r;
                if (row < N_)
                    P[(size_t)row * 512 + g * 128 + nt * 16 + l16] = (__bf16)acc[nt][r];
            }
        }
    }
}

// ---------------- counting sort by dst ----------------
__global__ void hist_kernel(const int* __restrict__ eidx, int* __restrict__ count, int E_) {
    int e = blockIdx.x * blockDim.x + threadIdx.x;
    if (e < E_) atomicAdd(&count[eidx[E_ + e]], 1);
}

__global__ __launch_bounds__(1024) void scan_kernel(const int* __restrict__ count,
                                                    int* __restrict__ cursor, int Nn) {
    __shared__ int part[1024];
    const int t = threadIdx.x;
    const int chunk = (Nn + 1023) >> 10;
    const int lo = t * chunk;
    const int hi = min(lo + chunk, Nn);
    int s = 0;
    for (int i = lo; i < hi; ++i) s += count[i];
    part[t] = s;
    __syncthreads();
    for (int off = 1; off < 1024; off <<= 1) {
        int v = (t >= off) ? part[t - off] : 0;
        __syncthreads();
        part[t] += v;
        __syncthreads();
    }
    int run = (t == 0) ? 0 : part[t - 1];
    for (int i = lo; i < hi; ++i) { cursor[i] = run; run += count[i]; }
}

__global__ void scatter_kernel(const int* __restrict__ eidx, int* __restrict__ cursor,
                               int* __restrict__ dstS, int* __restrict__ srcS,
                               int* __restrict__ perm, int E_) {
    int e = blockIdx.x * blockDim.x + threadIdx.x;
    if (e >= E_) return;
    int d = eidx[E_ + e];
    int p = atomicAdd(&cursor[d], 1);
    dstS[p] = d;
    srcS[p] = eidx[e];
    perm[p] = e;
}

// ---------------- main edge kernel (lightweight) ----------------
// h1 = mish(Pa[dst] + Pb[src] + b1)          (gathered, no GEMM)
// he = mish(eattr@We_e + Pe[src] + be)       (K=16 MFMA + gather)
// msg = (h1@W2 + b2) * he                    (the only per-edge GEMM, K=128)
// Block = 4 waves on the SAME 16 sorted edges; wave w owns channels [32w,32w+32).
// MFMA 16x16x32: A[m=lane&15][k=quad*8+j]; B from B^T rows; C/D r -> row quad*4+r.
__global__ __launch_bounds__(256, 4) void edge_kernel(
    const __bf16* __restrict__ P,
    const int* __restrict__ dstS, const int* __restrict__ srcS, const int* __restrict__ perm,
    const float* __restrict__ eattr,
    const __bf16* __restrict__ W2T, const float* __restrict__ b2,
    const __bf16* __restrict__ WeeT,
    const float* __restrict__ b1, const float* __restrict__ be,
    float* __restrict__ aggr, int E_, int nchunks)
{
    __shared__ __align__(16) __bf16 h1s[16][136];

    const int wid  = threadIdx.x >> 6;
    const int lane = threadIdx.x & 63;
    const int quad = lane >> 4;
    const int l16  = lane & 15;
    const int half = lane >> 5;
    const int c32  = lane & 31;
    const int tsel = (lane >> 4) & 1;

    const int n0 = 32 * wid + l16;        // C-layout col, tile 0
    const int n1 = 32 * wid + 16 + l16;   // tile 1
    const int chA = 32 * wid + quad * 8;  // A-layout channel base for h1 path

    // ---- persistent weights & biases (small) ----
    bf16x8 bw2[4][2], bwee[2];
    #pragma unroll
    for (int kt = 0; kt < 4; ++kt) {
        bw2[kt][0] = *reinterpret_cast<const bf16x8*>(W2T + n0 * 128 + kt * 32 + quad * 8);
        bw2[kt][1] = *reinterpret_cast<const bf16x8*>(W2T + n1 * 128 + kt * 32 + quad * 8);
    }
    bwee[0] = *reinterpret_cast<const bf16x8*>(WeeT + n0 * 32 + quad * 8);
    bwee[1] = *reinterpret_cast<const bf16x8*>(WeeT + n1 * 32 + quad * 8);
    float b1v[8];
    #pragma unroll
    for (int j = 0; j < 8; ++j) b1v[j] = b1[chA + j];
    const float bev[2] = { be[n0], be[n1] };
    const float bb2[2] = { b2[n0], b2[n1] };

    const f32x4 fz4 = {0.f, 0.f, 0.f, 0.f};

    for (int ch = blockIdx.x; ch < nchunks; ch += gridDim.x) {
        const int e0 = ch * 16;
        int em = e0 + l16; if (em > E_ - 1) em = E_ - 1;
        const int src_m = srcS[em];
        const int dst_m = dstS[em];
        const int pm    = perm[em];

        // ---- h1 = mish(Pa[dst] + Pb[src] + b1), this lane: edge l16, ch chA..chA+8 ----
        bf16x8 pav = *reinterpret_cast<const bf16x8*>(P + (size_t)dst_m * 512 + chA);
        bf16x8 pbv = *reinterpret_cast<const bf16x8*>(P + (size_t)src_m * 512 + 128 + chA);
        bf16x8 h1v;
        #pragma unroll
        for (int j = 0; j < 8; ++j) {
            float v = mish_f((float)pav[j] + (float)pbv[j] + b1v[j]);
            h1v[j] = (__bf16)v;
        }
        *reinterpret_cast<bf16x8*>(&h1s[l16][chA]) = h1v;

        // ---- he pre-activation: eattr @ We_e (K=16, padded 32) + Pe[src] ----
        bf16x8 ae;
        #pragma unroll
        for (int j = 0; j < 8; ++j) ae[j] = (__bf16)0.0f;
        if (quad < 2) {
            const float4* p = reinterpret_cast<const float4*>(eattr + (size_t)pm * 16 + quad * 8);
            float4 v0 = p[0], v1 = p[1];
            ae[0] = (__bf16)v0.x; ae[1] = (__bf16)v0.y; ae[2] = (__bf16)v0.z; ae[3] = (__bf16)v0.w;
            ae[4] = (__bf16)v1.x; ae[5] = (__bf16)v1.y; ae[6] = (__bf16)v1.z; ae[7] = (__bf16)v1.w;
        }
        f32x4 acce[2] = {fz4, fz4};
        acce[0] = __builtin_amdgcn_mfma_f32_16x16x32_bf16(ae, bwee[0], acce[0], 0, 0, 0);
        acce[1] = __builtin_amdgcn_mfma_f32_16x16x32_bf16(ae, bwee[1], acce[1], 0, 0, 0);
        // Pe gathers in C-layout: edge quad*4+r, channels n0/n1
        #pragma unroll
        for (int r = 0; r < 4; ++r) {
            int src_r = __shfl(src_m, quad * 4 + r);
            acce[0][r] += (float)P[(size_t)src_r * 512 + 256 + n0];
            acce[1][r] += (float)P[(size_t)src_r * 512 + 256 + n1];
        }

        __syncthreads();

        // ---- GEMM2: h1 @ W2, K=128 ----
        f32x4 acc2[2] = {fz4, fz4};
        #pragma unroll
        for (int kt = 0; kt < 4; ++kt) {
            bf16x8 a = *reinterpret_cast<const bf16x8*>(&h1s[l16][kt * 32 + quad * 8]);
            acc2[0] = __builtin_amdgcn_mfma_f32_16x16x32_bf16(a, bw2[kt][0], acc2[0], 0, 0, 0);
            acc2[1] = __builtin_amdgcn_mfma_f32_16x16x32_bf16(a, bw2[kt][1], acc2[1], 0, 0, 0);
        }
        __syncthreads();

        // ---- msg ----
        float m0[4], m1[4];
        #pragma unroll
        for (int r = 0; r < 4; ++r) {
            m0[r] = (acc2[0][r] + bb2[0]) * mish_f(acce[0][r] + bev[0]);
            m1[r] = (acc2[1][r] + bb2[1]) * mish_f(acce[1][r] + bev[1]);
        }

        // ---- shuffle segment reduction over sorted rows ----
        float racc = 0.f; int curd = -1;
        #pragma unroll
        for (int i = 0; i < 8; ++i) {
            int row  = 8 * half + i;
            int srcL = (row >> 2) * 16 + (c32 & 15);
            float v0 = __shfl(m0[i & 3], srcL);
            float v1 = __shfl(m1[i & 3], srcL);
            float v  = tsel ? v1 : v0;
            if (e0 + row >= E_) v = 0.f;
            int d = __shfl(dst_m, row);
            if (i == 0) { curd = d; racc = v; }
            else if (d != curd) {
                atomicAdd(aggr + (size_t)curd * 128 + 32 * wid + c32, racc);
                curd = d; racc = v;
            } else racc += v;
        }
        atomicAdd(aggr + (size_t)curd * 128 + 32 * wid + c32, racc);
    }
}

// ---------------- node stream: out = aggr + Proot + bias; BN partials ----------------
__global__ __launch_bounds__(256) void node_stream_kernel(
    const __bf16* __restrict__ P, const float* __restrict__ bias,
    float* __restrict__ out, float* __restrict__ stats, int N_)
{
    __shared__ float redS[8][32][8];
    const int c4  = threadIdx.x & 31;
    const int grp = threadIdx.x >> 5;
    float4 bb = reinterpret_cast<const float4*>(bias)[c4];
    float ps[4] = {0.f, 0.f, 0.f, 0.f}, pq[4] = {0.f, 0.f, 0.f, 0.f};

    for (int n = blockIdx.x * 8 + grp; n < N_; n += gridDim.x * 8) {
        float4 v = reinterpret_cast<float4*>(out)[(size_t)n * 32 + c4];
        bf16x4 pr = *reinterpret_cast<const bf16x4*>(P + (size_t)n * 512 + 384 + c4 * 4);
        v.x += (float)pr[0] + bb.x;
        v.y += (float)pr[1] + bb.y;
        v.z += (float)pr[2] + bb.z;
        v.w += (float)pr[3] + bb.w;
        reinterpret_cast<float4*>(out)[(size_t)n * 32 + c4] = v;
        ps[0] += v.x; ps[1] += v.y; ps[2] += v.z; ps[3] += v.w;
        pq[0] += v.x * v.x; pq[1] += v.y * v.y; pq[2] += v.z * v.z; pq[3] += v.w * v.w;
    }
    #pragma unroll
    for (int j = 0; j < 4; ++j) { redS[grp][c4][j] = ps[j]; redS[grp][c4][4 + j] = pq[j]; }
    __syncthreads();
    {
        const int cc = threadIdx.x & 31, jj = threadIdx.x >> 5;
        float s = 0.f;
        #pragma unroll
        for (int k = 0; k < 8; ++k) s += redS[k][cc][jj];
        if (jj < 4) atomicAdd(&stats[cc * 4 + jj], s);
        else        atomicAdd(&stats[128 + cc * 4 + (jj - 4)], s);
    }
}

// ---------------- BN finalize ----------------
__global__ void bn_kernel(float* __restrict__ out, const float* __restrict__ stats,
                          const float* __restrict__ gamma, const float* __restrict__ beta,
                          float invN, int total4)
{
    int i = blockIdx.x * blockDim.x + threadIdx.x;
    if (i >= total4) return;
    int c0 = (i & 31) * 4;
    float4 v = reinterpret_cast<float4*>(out)[i];
    float o[4] = {v.x, v.y, v.z, v.w};
    #pragma unroll
    for (int j = 0; j < 4; ++j) {
        int c = c0 + j;
        float mean  = stats[c] * invN;
        float var   = stats[128 + c] * invN - mean * mean;
        float scale = gamma[c] * rsqrtf(var + BN_EPS);
        o[j] = (o[j] - mean) * scale + beta[c];
    }
    v.x = o[0]; v.y = o[1]; v.z = o[2]; v.w = o[3];
    reinterpret_cast<float4*>(out)[i] = v;
}

extern "C" void kernel_launch(void* const* d_in, const int* in_sizes, int n_in,
                              void* d_out, int out_size, void* d_ws, size_t ws_size,
                              hipStream_t stream)
{
    const float* x     = (const float*)d_in[0];
    const int*   eidx  = (const int*)d_in[1];
    const float* eattr = (const float*)d_in[2];
    const float* W1    = (const float*)d_in[3];
    const float* b1    = (const float*)d_in[4];
    const float* W2    = (const float*)d_in[5];
    const float* b2    = (const float*)d_in[6];
    const float* We    = (const float*)d_in[7];
    const float* be    = (const float*)d_in[8];
    const float* Wroot = (const float*)d_in[9];
    const float* bias  = (const float*)d_in[10];
    const float* gamma = (const float*)d_in[11];
    const float* beta  = (const float*)d_in[12];

    const int N_ = in_sizes[0] / 128;
    const int E_ = in_sizes[1] / 2;

    char* ws = (char*)d_ws;
    size_t off = 0;
    __bf16* P     = (__bf16*)(ws + off); off += (size_t)N_ * 512 * 2;
    __bf16* WcatT = (__bf16*)(ws + off); off += 512 * 128 * 2;
    __bf16* W2T   = (__bf16*)(ws + off); off += 128 * 128 * 2;
    __bf16* WeeT  = (__bf16*)(ws + off); off += 128 * 32 * 2;
    float* stats  = (float*)(ws + off);  off += 256 * 4;
    off = (off + 15) & ~(size_t)15;
    int* count  = (int*)(ws + off); off += (size_t)N_ * 4;
    int* cursor = (int*)(ws + off); off += (size_t)N_ * 4;
    int* dstS   = (int*)(ws + off); off += (size_t)E_ * 4;
    int* srcS   = (int*)(ws + off); off += (size_t)E_ * 4;
    int* perm   = (int*)(ws + off); off += (size_t)E_ * 4;

    float* out = (float*)d_out;

    hipMemsetAsync(out, 0, (size_t)out_size * sizeof(float), stream);
    hipMemsetAsync(stats, 0, 256 * sizeof(float), stream);
    hipMemsetAsync(count, 0, (size_t)N_ * sizeof(int), stream);

    int wtot = 512 * 128 + 128 * 128 + 128 * 32;
    prep_w_kernel<<<(wtot + 255) / 256, 256, 0, stream>>>(W1, W2, We, Wroot, WcatT, W2T, WeeT);

    hist_kernel<<<(E_ + 255) / 256, 256, 0, stream>>>(eidx, count, E_);
    scan_kernel<<<1, 1024, 0, stream>>>(count, cursor, N_);
    scatter_kernel<<<(E_ + 255) / 256, 256, 0, stream>>>(eidx, cursor, dstS, srcS, perm, E_);

    precompute_kernel<<<(N_ + 63) / 64, 256, 0, stream>>>(x, WcatT, P, N_);

    int nchunks = (E_ + 15) / 16;
    edge_kernel<<<2048, 256, 0, stream>>>(P, dstS, srcS, perm, eattr,
                                          W2T, b2, WeeT, b1, be, out, E_, nchunks);

    node_stream_kernel<<<512, 256, 0, stream>>>(P, bias, out, stats, N_);

    bn_kernel<<<(N_ * 32 + 255) / 256, 256, 0, stream>>>(out, stats, gamma, beta,
                                                         1.0f / (float)N_, N_ * 32);
}

// Round 6
// 578.926 us; speedup vs baseline: 2.0953x; 1.0950x over previous
//
#include <hip/hip_runtime.h>

typedef __bf16 bf16x8 __attribute__((ext_vector_type(8)));
typedef __bf16 bf16x4 __attribute__((ext_vector_type(4)));
typedef float  f32x4  __attribute__((ext_vector_type(4)));

#define BN_EPS 1e-5f

__device__ __forceinline__ float mish_f(float x) {
    float xc = fminf(fmaxf(x, -30.0f), 30.0f);
    float u = __expf(xc);
    float num = u * (u + 2.0f);
    return x * __fdividef(num, num + 2.0f);
}

// ---------------- prep: weights -> fused B^T bf16 ----------------
// WcatT[512][128]: n<128 -> W1 rows 0..127 (x_i) | n<256 -> W1 rows 128..255 (x_j)
//                  n<384 -> We rows 16..143 (x_j) | n<512 -> Wroot
// W2T[128][128]; WeeT[128][32] (k<16 -> We rows 0..15 (eattr), else 0)
__global__ void prep_w_kernel(const float* __restrict__ W1, const float* __restrict__ W2,
                              const float* __restrict__ We, const float* __restrict__ Wr,
                              __bf16* __restrict__ WcatT, __bf16* __restrict__ W2T,
                              __bf16* __restrict__ WeeT) {
    int i = blockIdx.x * blockDim.x + threadIdx.x;
    if (i < 512 * 128) {
        int n = i >> 7, k = i & 127;
        float v;
        if (n < 128)      v = W1[k * 128 + n];
        else if (n < 256) v = W1[(128 + k) * 128 + (n - 128)];
        else if (n < 384) v = We[(16 + k) * 128 + (n - 256)];
        else              v = Wr[k * 128 + (n - 384)];
        WcatT[(size_t)n * 128 + k] = (__bf16)v;
    } else if (i < 512 * 128 + 128 * 128) {
        int j = i - 512 * 128;
        int n = j >> 7, k = j & 127;
        W2T[n * 128 + k] = (__bf16)W2[k * 128 + n];
    } else if (i < 512 * 128 + 128 * 128 + 128 * 32) {
        int j = i - (512 * 128 + 128 * 128);
        int n = j >> 5, k = j & 31;
        WeeT[n * 32 + k] = (k < 16) ? (__bf16)We[k * 128 + n] : (__bf16)0.0f;
    }
}

// ---------------- precompute P[n][512] = x[n] @ [W1a|W1b|We_x|Wroot] (bf16) ----------------
__global__ __launch_bounds__(256) void precompute_kernel(
    const float* __restrict__ x, const __bf16* __restrict__ WcatT,
    __bf16* __restrict__ P, int N_)
{
    const int wid  = threadIdx.x >> 6;
    const int lane = threadIdx.x & 63;
    const int quad = lane >> 4;
    const int l16  = lane & 15;

    int rl = blockIdx.x * 64 + wid * 16 + l16;
    if (rl > N_ - 1) rl = N_ - 1;

    bf16x8 a[4];
    #pragma unroll
    for (int kt = 0; kt < 4; ++kt) {
        const float4* p = reinterpret_cast<const float4*>(x + (size_t)rl * 128 + kt * 32 + quad * 8);
        float4 v0 = p[0], v1 = p[1];
        a[kt][0] = (__bf16)v0.x; a[kt][1] = (__bf16)v0.y; a[kt][2] = (__bf16)v0.z; a[kt][3] = (__bf16)v0.w;
        a[kt][4] = (__bf16)v1.x; a[kt][5] = (__bf16)v1.y; a[kt][6] = (__bf16)v1.z; a[kt][7] = (__bf16)v1.w;
    }

    const f32x4 fz4 = {0.f, 0.f, 0.f, 0.f};
    #pragma unroll
    for (int g = 0; g < 4; ++g) {
        f32x4 acc[8];
        #pragma unroll
        for (int nt = 0; nt < 8; ++nt) acc[nt] = fz4;
        #pragma unroll
        for (int kt = 0; kt < 4; ++kt) {
            #pragma unroll
            for (int nt = 0; nt < 8; ++nt) {
                bf16x8 b = *reinterpret_cast<const bf16x8*>(
                    WcatT + (size_t)((g * 8 + nt) * 16 + l16) * 128 + kt * 32 + quad * 8);
                acc[nt] = __builtin_amdgcn_mfma_f32_16x16x32_bf16(a[kt], b, acc[nt], 0, 0, 0);
            }
        }
        #pragma unroll
        for (int nt = 0; nt < 8; ++nt) {
            #pragma unroll
            for (int r = 0; r < 4; ++r) {
                int row = blockIdx.x * 64 + wid * 16 + quad * 4 + r;
                if (row < N_)
                    P[(size_t)row * 512 + g * 128 + nt * 16 + l16] = (__bf16)acc[nt][r];
            }
        }
    }
}

// ---------------- counting sort by dst (parallel scan version) ----------------
__global__ void hist_kernel(const int* __restrict__ eidx, int* __restrict__ count, int E_) {
    int e = blockIdx.x * blockDim.x + threadIdx.x;
    if (e < E_) atomicAdd(&count[eidx[E_ + e]], 1);
}

// scanA: per-block (4096 elems) exclusive prefix into cursor, block sums out
__global__ __launch_bounds__(1024) void scanA_kernel(const int* __restrict__ count,
                                                     int* __restrict__ cursor,
                                                     int* __restrict__ bsums, int Nn) {
    __shared__ int waveS[16];
    const int t = threadIdx.x;
    const int lane = t & 63;
    const int wv = t >> 6;
    const int i0 = blockIdx.x * 4096 + t * 4;
    int c0 = 0, c1 = 0, c2 = 0, c3 = 0;
    if (i0 + 3 < Nn) {
        int4 c = *reinterpret_cast<const int4*>(count + i0);
        c0 = c.x; c1 = c.y; c2 = c.z; c3 = c.w;
    } else if (i0 < Nn) {
        c0 = count[i0];
        if (i0 + 1 < Nn) c1 = count[i0 + 1];
        if (i0 + 2 < Nn) c2 = count[i0 + 2];
    }
    int s1 = c0 + c1, s2 = s1 + c2, tot = s2 + c3;
    int x = tot;
    #pragma unroll
    for (int s = 1; s < 64; s <<= 1) {
        int y = __shfl(x, (lane >= s) ? (lane - s) : lane);
        if (lane >= s) x += y;
    }
    if (lane == 63) waveS[wv] = x;
    __syncthreads();
    if (t == 0) {
        int run = 0;
        #pragma unroll
        for (int w = 0; w < 16; ++w) { int v = waveS[w]; waveS[w] = run; run += v; }
        bsums[blockIdx.x] = run;
    }
    __syncthreads();
    int excl = waveS[wv] + (x - tot);
    if (i0 + 3 < Nn) {
        int4 o; o.x = excl; o.y = excl + c0; o.z = excl + s1; o.w = excl + s2;
        *reinterpret_cast<int4*>(cursor + i0) = o;
    } else if (i0 < Nn) {
        cursor[i0] = excl;
        if (i0 + 1 < Nn) cursor[i0 + 1] = excl + c0;
        if (i0 + 2 < Nn) cursor[i0 + 2] = excl + s1;
    }
}

// scanB: add block offsets
__global__ __launch_bounds__(1024) void scanB_kernel(int* __restrict__ cursor,
                                                     const int* __restrict__ bsums, int Nn) {
    __shared__ int offS;
    const int b = blockIdx.x;
    if (threadIdx.x == 0) {
        int s = 0;
        for (int i = 0; i < b; ++i) s += bsums[i];
        offS = s;
    }
    __syncthreads();
    const int o = offS;
    if (b == 0) return;
    const int i0 = b * 4096 + threadIdx.x * 4;
    if (i0 + 3 < Nn) {
        int4 v = *reinterpret_cast<int4*>(cursor + i0);
        v.x += o; v.y += o; v.z += o; v.w += o;
        *reinterpret_cast<int4*>(cursor + i0) = v;
    } else {
        #pragma unroll
        for (int j = 0; j < 4; ++j) if (i0 + j < Nn) cursor[i0 + j] += o;
    }
}

// scatter: one packed int4 store per edge
__global__ void scatter_kernel(const int* __restrict__ eidx, int* __restrict__ cursor,
                               int4* __restrict__ edgesS, int E_) {
    int e = blockIdx.x * blockDim.x + threadIdx.x;
    if (e >= E_) return;
    int d = eidx[E_ + e];
    int p = atomicAdd(&cursor[d], 1);
    edgesS[p] = make_int4(d, eidx[e], e, 0);
}

// ---------------- main edge kernel ----------------
// msg is computed TRANSPOSED: D[ch][edge] via A=W2^T frags, B=h1 rows from LDS.
//   C/D: reg r -> ch = tilebase + quad*4 + r ; col = lane&15 -> edge.
// he path: ee = (eattr @ We_e)^T via A=WeeT frags, B=eattr frag; Pe is a 4-ch
// VECTOR load (ch = quad*4+r contiguous). Segment reduction = 4-step segmented
// shuffle scan along lanes (edge dim); tail lanes fire the atomics.
__global__ __launch_bounds__(256, 4) void edge_kernel(
    const __bf16* __restrict__ P,
    const int4* __restrict__ edgesS,
    const float* __restrict__ eattr,
    const __bf16* __restrict__ W2T, const float* __restrict__ b2,
    const __bf16* __restrict__ WeeT,
    const float* __restrict__ b1, const float* __restrict__ be,
    float* __restrict__ aggr, int E_, int nchunks)
{
    __shared__ __align__(16) __bf16 h1s[16][136];

    const int wid  = threadIdx.x >> 6;
    const int lane = threadIdx.x & 63;
    const int quad = lane >> 4;
    const int l16  = lane & 15;
    const int lb   = lane & 48;          // quad base lane

    const int tb0 = 32 * wid;            // ch tile bases for this wave
    const int tb1 = 32 * wid + 16;
    const int chA = 32 * wid + quad * 8; // row-layout channel base (h1 path)

    // ---- resident A fragments: W2^T (ch x k) and WeeT (ch x k) ----
    bf16x8 aw2[4][2], awe[2];
    #pragma unroll
    for (int kt = 0; kt < 4; ++kt) {
        aw2[kt][0] = *reinterpret_cast<const bf16x8*>(W2T + (tb0 + l16) * 128 + kt * 32 + quad * 8);
        aw2[kt][1] = *reinterpret_cast<const bf16x8*>(W2T + (tb1 + l16) * 128 + kt * 32 + quad * 8);
    }
    awe[0] = *reinterpret_cast<const bf16x8*>(WeeT + (tb0 + l16) * 32 + quad * 8);
    awe[1] = *reinterpret_cast<const bf16x8*>(WeeT + (tb1 + l16) * 32 + quad * 8);

    // biases: per-reg (ch = tb + quad*4 + r) vectors; per-lane (chA+j) array
    const f32x4 b2v0 = *reinterpret_cast<const f32x4*>(b2 + tb0 + quad * 4);
    const f32x4 b2v1 = *reinterpret_cast<const f32x4*>(b2 + tb1 + quad * 4);
    const f32x4 bev0 = *reinterpret_cast<const f32x4*>(be + tb0 + quad * 4);
    const f32x4 bev1 = *reinterpret_cast<const f32x4*>(be + tb1 + quad * 4);
    const f32x4 b1a = *reinterpret_cast<const f32x4*>(b1 + chA);
    const f32x4 b1b = *reinterpret_cast<const f32x4*>(b1 + chA + 4);
    float b1v[8] = { b1a[0], b1a[1], b1a[2], b1a[3], b1b[0], b1b[1], b1b[2], b1b[3] };

    const f32x4 fz4 = {0.f, 0.f, 0.f, 0.f};

    for (int ch = blockIdx.x; ch < nchunks; ch += gridDim.x) {
        const int e0 = ch * 16;
        int em = e0 + l16; if (em > E_ - 1) em = E_ - 1;
        const int4 er = edgesS[em];
        const int dst_m = er.x, src_m = er.y, pm = er.z;

        // ---- h1 = mish(Pa[dst] + Pb[src] + b1), row layout ----
        bf16x8 pav = *reinterpret_cast<const bf16x8*>(P + (size_t)dst_m * 512 + chA);
        bf16x8 pbv = *reinterpret_cast<const bf16x8*>(P + (size_t)src_m * 512 + 128 + chA);
        bf16x8 h1v;
        #pragma unroll
        for (int j = 0; j < 8; ++j)
            h1v[j] = (__bf16)mish_f((float)pav[j] + (float)pbv[j] + b1v[j]);
        *reinterpret_cast<bf16x8*>(&h1s[l16][chA]) = h1v;

        // ---- B-frag for ee: eattr[pm] (k = quad*8+j; real only k<16) ----
        bf16x8 ae;
        #pragma unroll
        for (int j = 0; j < 8; ++j) ae[j] = (__bf16)0.0f;
        if (quad < 2) {
            const float4* p = reinterpret_cast<const float4*>(eattr + (size_t)pm * 16 + quad * 8);
            float4 v0 = p[0], v1 = p[1];
            ae[0] = (__bf16)v0.x; ae[1] = (__bf16)v0.y; ae[2] = (__bf16)v0.z; ae[3] = (__bf16)v0.w;
            ae[4] = (__bf16)v1.x; ae[5] = (__bf16)v1.y; ae[6] = (__bf16)v1.z; ae[7] = (__bf16)v1.w;
        }

        // ---- Pe vector loads: 4 consecutive ch per tile ----
        bf16x4 pe0 = *reinterpret_cast<const bf16x4*>(P + (size_t)src_m * 512 + 256 + tb0 + quad * 4);
        bf16x4 pe1 = *reinterpret_cast<const bf16x4*>(P + (size_t)src_m * 512 + 256 + tb1 + quad * 4);

        __syncthreads();   // h1s ready

        // ---- GEMM2 (transposed): D[ch][edge] ----
        f32x4 acc2[2] = {fz4, fz4};
        #pragma unroll
        for (int kt = 0; kt < 4; ++kt) {
            bf16x8 bf = *reinterpret_cast<const bf16x8*>(&h1s[l16][kt * 32 + quad * 8]);
            acc2[0] = __builtin_amdgcn_mfma_f32_16x16x32_bf16(aw2[kt][0], bf, acc2[0], 0, 0, 0);
            acc2[1] = __builtin_amdgcn_mfma_f32_16x16x32_bf16(aw2[kt][1], bf, acc2[1], 0, 0, 0);
        }
        __syncthreads();   // h1s consumed

        // ---- ee (transposed) + msg ----
        f32x4 acce[2] = {fz4, fz4};
        acce[0] = __builtin_amdgcn_mfma_f32_16x16x32_bf16(awe[0], ae, acce[0], 0, 0, 0);
        acce[1] = __builtin_amdgcn_mfma_f32_16x16x32_bf16(awe[1], ae, acce[1], 0, 0, 0);

        f32x4 v0, v1;
        #pragma unroll
        for (int r = 0; r < 4; ++r) {
            float he0 = mish_f(acce[0][r] + (float)pe0[r] + bev0[r]);
            float he1 = mish_f(acce[1][r] + (float)pe1[r] + bev1[r]);
            v0[r] = (acc2[0][r] + b2v0[r]) * he0;
            v1[r] = (acc2[1][r] + b2v1[r]) * he1;
        }
        if (e0 + l16 >= E_) { v0 = fz4; v1 = fz4; }

        // ---- segmented inclusive scan across the quad's 16 lanes (edges) ----
        int dprev = __shfl(dst_m, lb + ((l16 + 15) & 15));
        int dnext = __shfl(dst_m, lb + ((l16 + 1) & 15));
        unsigned f = (l16 == 0 || dprev != dst_m) ? 1u : 0u;
        const bool tail = (l16 == 15) || (dnext != dst_m);
        #pragma unroll
        for (int s = 1; s < 16; s <<= 1) {
            int srcl = (l16 >= s) ? (lane - s) : lane;
            f32x4 u0, u1;
            #pragma unroll
            for (int r = 0; r < 4; ++r) { u0[r] = __shfl(v0[r], srcl); u1[r] = __shfl(v1[r], srcl); }
            unsigned fu = (unsigned)__shfl((int)f, srcl);
            if (l16 >= s) {
                if (!f) { v0 += u0; v1 += u1; }
                f |= fu;
            }
        }
        if (tail) {
            float* base = aggr + (size_t)dst_m * 128;
            #pragma unroll
            for (int r = 0; r < 4; ++r) atomicAdd(base + tb0 + quad * 4 + r, v0[r]);
            #pragma unroll
            for (int r = 0; r < 4; ++r) atomicAdd(base + tb1 + quad * 4 + r, v1[r]);
        }
    }
}

// ---------------- node stream: out = aggr + Proot + bias; BN partials ----------------
__global__ __launch_bounds__(256) void node_stream_kernel(
    const __bf16* __restrict__ P, const float* __restrict__ bias,
    float* __restrict__ out, float* __restrict__ stats, int N_)
{
    __shared__ float redS[8][32][8];
    const int c4  = threadIdx.x & 31;
    const int grp = threadIdx.x >> 5;
    float4 bb = reinterpret_cast<const float4*>(bias)[c4];
    float ps[4] = {0.f, 0.f, 0.f, 0.f}, pq[4] = {0.f, 0.f, 0.f, 0.f};

    for (int n = blockIdx.x * 8 + grp; n < N_; n += gridDim.x * 8) {
        float4 v = reinterpret_cast<float4*>(out)[(size_t)n * 32 + c4];
        bf16x4 pr = *reinterpret_cast<const bf16x4*>(P + (size_t)n * 512 + 384 + c4 * 4);
        v.x += (float)pr[0] + bb.x;
        v.y += (float)pr[1] + bb.y;
        v.z += (float)pr[2] + bb.z;
        v.w += (float)pr[3] + bb.w;
        reinterpret_cast<float4*>(out)[(size_t)n * 32 + c4] = v;
        ps[0] += v.x; ps[1] += v.y; ps[2] += v.z; ps[3] += v.w;
        pq[0] += v.x * v.x; pq[1] += v.y * v.y; pq[2] += v.z * v.z; pq[3] += v.w * v.w;
    }
    #pragma unroll
    for (int j = 0; j < 4; ++j) { redS[grp][c4][j] = ps[j]; redS[grp][c4][4 + j] = pq[j]; }
    __syncthreads();
    {
        const int cc = threadIdx.x & 31, jj = threadIdx.x >> 5;
        float s = 0.f;
        #pragma unroll
        for (int k = 0; k < 8; ++k) s += redS[k][cc][jj];
        if (jj < 4) atomicAdd(&stats[cc * 4 + jj], s);
        else        atomicAdd(&stats[128 + cc * 4 + (jj - 4)], s);
    }
}

// ---------------- BN finalize ----------------
__global__ void bn_kernel(float* __restrict__ out, const float* __restrict__ stats,
                          const float* __restrict__ gamma, const float* __restrict__ beta,
                          float invN, int total4)
{
    int i = blockIdx.x * blockDim.x + threadIdx.x;
    if (i >= total4) return;
    int c0 = (i & 31) * 4;
    float4 v = reinterpret_cast<float4*>(out)[i];
    float o[4] = {v.x, v.y, v.z, v.w};
    #pragma unroll
    for (int j = 0; j < 4; ++j) {
        int c = c0 + j;
        float mean  = stats[c] * invN;
        float var   = stats[128 + c] * invN - mean * mean;
        float scale = gamma[c] * rsqrtf(var + BN_EPS);
        o[j] = (o[j] - mean) * scale + beta[c];
    }
    v.x = o[0]; v.y = o[1]; v.z = o[2]; v.w = o[3];
    reinterpret_cast<float4*>(out)[i] = v;
}

extern "C" void kernel_launch(void* const* d_in, const int* in_sizes, int n_in,
                              void* d_out, int out_size, void* d_ws, size_t ws_size,
                              hipStream_t stream)
{
    const float* x     = (const float*)d_in[0];
    const int*   eidx  = (const int*)d_in[1];
    const float* eattr = (const float*)d_in[2];
    const float* W1    = (const float*)d_in[3];
    const float* b1    = (const float*)d_in[4];
    const float* W2    = (const float*)d_in[5];
    const float* b2    = (const float*)d_in[6];
    const float* We    = (const float*)d_in[7];
    const float* be    = (const float*)d_in[8];
    const float* Wroot = (const float*)d_in[9];
    const float* bias  = (const float*)d_in[10];
    const float* gamma = (const float*)d_in[11];
    const float* beta  = (const float*)d_in[12];

    const int N_ = in_sizes[0] / 128;
    const int E_ = in_sizes[1] / 2;

    char* ws = (char*)d_ws;
    size_t off = 0;
    __bf16* P     = (__bf16*)(ws + off); off += (size_t)N_ * 512 * 2;
    __bf16* WcatT = (__bf16*)(ws + off); off += 512 * 128 * 2;
    __bf16* W2T   = (__bf16*)(ws + off); off += 128 * 128 * 2;
    __bf16* WeeT  = (__bf16*)(ws + off); off += 128 * 32 * 2;
    off = (off + 15) & ~(size_t)15;
    float* stats  = (float*)(ws + off);  off += 256 * 4;       // stats+count: one memset
    int* count    = (int*)(ws + off);    off += (size_t)N_ * 4;
    size_t zero_bytes = 256 * 4 + (size_t)N_ * 4;
    int* cursor   = (int*)(ws + off);    off += (size_t)N_ * 4;
    int* bsums    = (int*)(ws + off);    off += 64 * 4;
    off = (off + 15) & ~(size_t)15;
    int4* edgesS  = (int4*)(ws + off);   off += (size_t)E_ * 16;

    float* out = (float*)d_out;

    hipMemsetAsync(out, 0, (size_t)out_size * sizeof(float), stream);
    hipMemsetAsync(stats, 0, zero_bytes, stream);

    int wtot = 512 * 128 + 128 * 128 + 128 * 32;
    prep_w_kernel<<<(wtot + 255) / 256, 256, 0, stream>>>(W1, W2, We, Wroot, WcatT, W2T, WeeT);

    hist_kernel<<<(E_ + 255) / 256, 256, 0, stream>>>(eidx, count, E_);
    int nb = (N_ + 4095) / 4096;
    scanA_kernel<<<nb, 1024, 0, stream>>>(count, cursor, bsums, N_);
    scanB_kernel<<<nb, 1024, 0, stream>>>(cursor, bsums, N_);
    scatter_kernel<<<(E_ + 255) / 256, 256, 0, stream>>>(eidx, cursor, edgesS, E_);

    precompute_kernel<<<(N_ + 63) / 64, 256, 0, stream>>>(x, WcatT, P, N_);

    int nchunks = (E_ + 15) / 16;
    edge_kernel<<<2048, 256, 0, stream>>>(P, edgesS, eattr,
                                          W2T, b2, WeeT, b1, be, out, E_, nchunks);

    node_stream_kernel<<<512, 256, 0, stream>>>(P, bias, out, stats, N_);

    bn_kernel<<<(N_ * 32 + 255) / 256, 256, 0, stream>>>(out, stats, gamma, beta,
                                                         1.0f / (float)N_, N_ * 32);
}

// Round 7
// 544.599 us; speedup vs baseline: 2.2273x; 1.0630x over previous
//
#include <hip/hip_runtime.h>

typedef __bf16 bf16x8 __attribute__((ext_vector_type(8)));
typedef __bf16 bf16x4 __attribute__((ext_vector_type(4)));
typedef float  f32x4  __attribute__((ext_vector_type(4)));

#define BN_EPS 1e-5f

__device__ __forceinline__ float mish_f(float x) {
    // upper clamp only: exp(-inf)->0 is safe (num->0, den->2, result->0)
    float xc = fminf(x, 30.0f);
    float u = __expf(xc);
    float num = u * (u + 2.0f);
    return x * __fdividef(num, num + 2.0f);
}

// ---------------- fused prep: weights -> B^T bf16  +  dst histogram ----------------
// WcatT[512][128]: n<128 -> W1 rows 0..127 (x_i) | n<256 -> W1 rows 128..255 (x_j)
//                  n<384 -> We rows 16..143 (x_j) | n<512 -> Wroot
// W2T[128][128]; WeeT[128][32] (k<16 -> We rows 0..15 (eattr), else 0)
__global__ void prep_hist_kernel(const float* __restrict__ W1, const float* __restrict__ W2,
                                 const float* __restrict__ We, const float* __restrict__ Wr,
                                 __bf16* __restrict__ WcatT, __bf16* __restrict__ W2T,
                                 __bf16* __restrict__ WeeT,
                                 const int* __restrict__ eidx, int* __restrict__ count,
                                 int E_, int wblocks) {
    if ((int)blockIdx.x < wblocks) {
        int i = blockIdx.x * 256 + threadIdx.x;
        if (i < 512 * 128) {
            int n = i >> 7, k = i & 127;
            float v;
            if (n < 128)      v = W1[k * 128 + n];
            else if (n < 256) v = W1[(128 + k) * 128 + (n - 128)];
            else if (n < 384) v = We[(16 + k) * 128 + (n - 256)];
            else              v = Wr[k * 128 + (n - 384)];
            WcatT[(size_t)n * 128 + k] = (__bf16)v;
        } else if (i < 512 * 128 + 128 * 128) {
            int j = i - 512 * 128;
            int n = j >> 7, k = j & 127;
            W2T[n * 128 + k] = (__bf16)W2[k * 128 + n];
        } else if (i < 512 * 128 + 128 * 128 + 128 * 32) {
            int j = i - (512 * 128 + 128 * 128);
            int n = j >> 5, k = j & 31;
            WeeT[n * 32 + k] = (k < 16) ? (__bf16)We[k * 128 + n] : (__bf16)0.0f;
        }
    } else {
        int e = (blockIdx.x - wblocks) * 256 + threadIdx.x;
        if (e < E_) atomicAdd(&count[eidx[E_ + e]], 1);
    }
}

// ---------------- precompute P[n][512] = x[n] @ [W1a|W1b|We_x|Wroot] (bf16) ----------------
__global__ __launch_bounds__(256) void precompute_kernel(
    const float* __restrict__ x, const __bf16* __restrict__ WcatT,
    __bf16* __restrict__ P, int N_)
{
    const int wid  = threadIdx.x >> 6;
    const int lane = threadIdx.x & 63;
    const int quad = lane >> 4;
    const int l16  = lane & 15;

    int rl = blockIdx.x * 64 + wid * 16 + l16;
    if (rl > N_ - 1) rl = N_ - 1;

    bf16x8 a[4];
    #pragma unroll
    for (int kt = 0; kt < 4; ++kt) {
        const float4* p = reinterpret_cast<const float4*>(x + (size_t)rl * 128 + kt * 32 + quad * 8);
        float4 v0 = p[0], v1 = p[1];
        a[kt][0] = (__bf16)v0.x; a[kt][1] = (__bf16)v0.y; a[kt][2] = (__bf16)v0.z; a[kt][3] = (__bf16)v0.w;
        a[kt][4] = (__bf16)v1.x; a[kt][5] = (__bf16)v1.y; a[kt][6] = (__bf16)v1.z; a[kt][7] = (__bf16)v1.w;
    }

    const f32x4 fz4 = {0.f, 0.f, 0.f, 0.f};
    #pragma unroll
    for (int g = 0; g < 4; ++g) {
        f32x4 acc[8];
        #pragma unroll
        for (int nt = 0; nt < 8; ++nt) acc[nt] = fz4;
        #pragma unroll
        for (int kt = 0; kt < 4; ++kt) {
            #pragma unroll
            for (int nt = 0; nt < 8; ++nt) {
                bf16x8 b = *reinterpret_cast<const bf16x8*>(
                    WcatT + (size_t)((g * 8 + nt) * 16 + l16) * 128 + kt * 32 + quad * 8);
                acc[nt] = __builtin_amdgcn_mfma_f32_16x16x32_bf16(a[kt], b, acc[nt], 0, 0, 0);
            }
        }
        #pragma unroll
        for (int nt = 0; nt < 8; ++nt) {
            #pragma unroll
            for (int r = 0; r < 4; ++r) {
                int row = blockIdx.x * 64 + wid * 16 + quad * 4 + r;
                if (row < N_)
                    P[(size_t)row * 512 + g * 128 + nt * 16 + l16] = (__bf16)acc[nt][r];
            }
        }
    }
}

// ---------------- counting sort by dst (parallel scan) ----------------
__global__ __launch_bounds__(1024) void scanA_kernel(const int* __restrict__ count,
                                                     int* __restrict__ cursor,
                                                     int* __restrict__ bsums, int Nn) {
    __shared__ int waveS[16];
    const int t = threadIdx.x;
    const int lane = t & 63;
    const int wv = t >> 6;
    const int i0 = blockIdx.x * 4096 + t * 4;
    int c0 = 0, c1 = 0, c2 = 0, c3 = 0;
    if (i0 + 3 < Nn) {
        int4 c = *reinterpret_cast<const int4*>(count + i0);
        c0 = c.x; c1 = c.y; c2 = c.z; c3 = c.w;
    } else if (i0 < Nn) {
        c0 = count[i0];
        if (i0 + 1 < Nn) c1 = count[i0 + 1];
        if (i0 + 2 < Nn) c2 = count[i0 + 2];
    }
    int s1 = c0 + c1, s2 = s1 + c2, tot = s2 + c3;
    int x = tot;
    #pragma unroll
    for (int s = 1; s < 64; s <<= 1) {
        int y = __shfl(x, (lane >= s) ? (lane - s) : lane);
        if (lane >= s) x += y;
    }
    if (lane == 63) waveS[wv] = x;
    __syncthreads();
    if (t == 0) {
        int run = 0;
        #pragma unroll
        for (int w = 0; w < 16; ++w) { int v = waveS[w]; waveS[w] = run; run += v; }
        bsums[blockIdx.x] = run;
    }
    __syncthreads();
    int excl = waveS[wv] + (x - tot);
    if (i0 + 3 < Nn) {
        int4 o; o.x = excl; o.y = excl + c0; o.z = excl + s1; o.w = excl + s2;
        *reinterpret_cast<int4*>(cursor + i0) = o;
    } else if (i0 < Nn) {
        cursor[i0] = excl;
        if (i0 + 1 < Nn) cursor[i0 + 1] = excl + c0;
        if (i0 + 2 < Nn) cursor[i0 + 2] = excl + s1;
    }
}

__global__ __launch_bounds__(1024) void scanB_kernel(int* __restrict__ cursor,
                                                     const int* __restrict__ bsums, int Nn) {
    __shared__ int offS;
    const int b = blockIdx.x;
    if (threadIdx.x == 0) {
        int s = 0;
        for (int i = 0; i < b; ++i) s += bsums[i];
        offS = s;
    }
    __syncthreads();
    const int o = offS;
    if (b == 0) return;
    const int i0 = b * 4096 + threadIdx.x * 4;
    if (i0 + 3 < Nn) {
        int4 v = *reinterpret_cast<int4*>(cursor + i0);
        v.x += o; v.y += o; v.z += o; v.w += o;
        *reinterpret_cast<int4*>(cursor + i0) = v;
    } else {
        #pragma unroll
        for (int j = 0; j < 4; ++j) if (i0 + j < Nn) cursor[i0 + j] += o;
    }
}

__global__ void scatter_kernel(const int* __restrict__ eidx, int* __restrict__ cursor,
                               int4* __restrict__ edgesS, int E_) {
    int e = blockIdx.x * blockDim.x + threadIdx.x;
    if (e >= E_) return;
    int d = eidx[E_ + e];
    int p = atomicAdd(&cursor[d], 1);
    edgesS[p] = make_int4(d, eidx[e], e, 0);
}

// ---------------- main edge kernel ----------------
// msg computed TRANSPOSED (D[ch][edge]) via A=W2^T frags, B=h1 rows from LDS,
// then staged to WAVE-LOCAL LDS [edge][ch_local] and reduced R5-style:
// lane=channel (32 consecutive ch across the wave) -> wave-coalesced atomics.
__global__ __launch_bounds__(256, 4) void edge_kernel(
    const __bf16* __restrict__ P,
    const int4* __restrict__ edgesS,
    const float* __restrict__ eattr,
    const __bf16* __restrict__ W2T, const float* __restrict__ b2,
    const __bf16* __restrict__ WeeT,
    const float* __restrict__ b1, const float* __restrict__ be,
    float* __restrict__ aggr, int E_, int nchunks)
{
    __shared__ __align__(16) __bf16 h1s[16][136];
    __shared__ __align__(16) float msgS[4][16][36];  // wave-local msg [edge][ch_local]
    __shared__ int dsts[4][16];

    const int wid  = threadIdx.x >> 6;
    const int lane = threadIdx.x & 63;
    const int quad = lane >> 4;
    const int l16  = lane & 15;
    const int half = lane >> 5;
    const int c32  = lane & 31;

    const int tb0 = 32 * wid;            // ch tile bases for this wave
    const int tb1 = 32 * wid + 16;
    const int chA = 32 * wid + quad * 8; // row-layout channel base (h1 path)

    // ---- resident A fragments: W2^T (ch x k) and WeeT (ch x k) ----
    bf16x8 aw2[4][2], awe[2];
    #pragma unroll
    for (int kt = 0; kt < 4; ++kt) {
        aw2[kt][0] = *reinterpret_cast<const bf16x8*>(W2T + (tb0 + l16) * 128 + kt * 32 + quad * 8);
        aw2[kt][1] = *reinterpret_cast<const bf16x8*>(W2T + (tb1 + l16) * 128 + kt * 32 + quad * 8);
    }
    awe[0] = *reinterpret_cast<const bf16x8*>(WeeT + (tb0 + l16) * 32 + quad * 8);
    awe[1] = *reinterpret_cast<const bf16x8*>(WeeT + (tb1 + l16) * 32 + quad * 8);

    const f32x4 b2v0 = *reinterpret_cast<const f32x4*>(b2 + tb0 + quad * 4);
    const f32x4 b2v1 = *reinterpret_cast<const f32x4*>(b2 + tb1 + quad * 4);
    const f32x4 bev0 = *reinterpret_cast<const f32x4*>(be + tb0 + quad * 4);
    const f32x4 bev1 = *reinterpret_cast<const f32x4*>(be + tb1 + quad * 4);
    const f32x4 b1a = *reinterpret_cast<const f32x4*>(b1 + chA);
    const f32x4 b1b = *reinterpret_cast<const f32x4*>(b1 + chA + 4);
    float b1v[8] = { b1a[0], b1a[1], b1a[2], b1a[3], b1b[0], b1b[1], b1b[2], b1b[3] };

    const f32x4 fz4 = {0.f, 0.f, 0.f, 0.f};

    for (int ch = blockIdx.x; ch < nchunks; ch += gridDim.x) {
        const int e0 = ch * 16;
        int em = e0 + l16; if (em > E_ - 1) em = E_ - 1;
        const int4 er = edgesS[em];
        const int dst_m = er.x, src_m = er.y, pm = er.z;
        if (quad == 0) dsts[wid][l16] = dst_m;

        // ---- h1 = mish(Pa[dst] + Pb[src] + b1), row layout ----
        bf16x8 pav = *reinterpret_cast<const bf16x8*>(P + (size_t)dst_m * 512 + chA);
        bf16x8 pbv = *reinterpret_cast<const bf16x8*>(P + (size_t)src_m * 512 + 128 + chA);
        bf16x8 h1v;
        #pragma unroll
        for (int j = 0; j < 8; ++j)
            h1v[j] = (__bf16)mish_f((float)pav[j] + (float)pbv[j] + b1v[j]);
        *reinterpret_cast<bf16x8*>(&h1s[l16][chA]) = h1v;

        // ---- B-frag for ee: eattr[pm] (k = quad*8+j; real only k<16) ----
        bf16x8 ae;
        #pragma unroll
        for (int j = 0; j < 8; ++j) ae[j] = (__bf16)0.0f;
        if (quad < 2) {
            const float4* p = reinterpret_cast<const float4*>(eattr + (size_t)pm * 16 + quad * 8);
            float4 v0_ = p[0], v1_ = p[1];
            ae[0] = (__bf16)v0_.x; ae[1] = (__bf16)v0_.y; ae[2] = (__bf16)v0_.z; ae[3] = (__bf16)v0_.w;
            ae[4] = (__bf16)v1_.x; ae[5] = (__bf16)v1_.y; ae[6] = (__bf16)v1_.z; ae[7] = (__bf16)v1_.w;
        }

        // ---- Pe vector loads: 4 consecutive ch per tile ----
        bf16x4 pe0 = *reinterpret_cast<const bf16x4*>(P + (size_t)src_m * 512 + 256 + tb0 + quad * 4);
        bf16x4 pe1 = *reinterpret_cast<const bf16x4*>(P + (size_t)src_m * 512 + 256 + tb1 + quad * 4);

        __syncthreads();   // h1s ready

        // ---- GEMM2 (transposed): D[ch][edge] ----
        f32x4 acc2[2] = {fz4, fz4};
        #pragma unroll
        for (int kt = 0; kt < 4; ++kt) {
            bf16x8 bf = *reinterpret_cast<const bf16x8*>(&h1s[l16][kt * 32 + quad * 8]);
            acc2[0] = __builtin_amdgcn_mfma_f32_16x16x32_bf16(aw2[kt][0], bf, acc2[0], 0, 0, 0);
            acc2[1] = __builtin_amdgcn_mfma_f32_16x16x32_bf16(aw2[kt][1], bf, acc2[1], 0, 0, 0);
        }
        __syncthreads();   // h1s consumed

        // ---- ee (transposed) + msg ----
        f32x4 acce[2] = {fz4, fz4};
        acce[0] = __builtin_amdgcn_mfma_f32_16x16x32_bf16(awe[0], ae, acce[0], 0, 0, 0);
        acce[1] = __builtin_amdgcn_mfma_f32_16x16x32_bf16(awe[1], ae, acce[1], 0, 0, 0);

        f32x4 v0, v1;
        #pragma unroll
        for (int r = 0; r < 4; ++r) {
            float he0 = mish_f(acce[0][r] + (float)pe0[r] + bev0[r]);
            float he1 = mish_f(acce[1][r] + (float)pe1[r] + bev1[r]);
            v0[r] = (acc2[0][r] + b2v0[r]) * he0;
            v1[r] = (acc2[1][r] + b2v1[r]) * he1;
        }
        if (e0 + l16 >= E_) { v0 = fz4; v1 = fz4; }

        // ---- stage msg to wave-local LDS: [edge l16][ch_local] ----
        // D[ch][edge]: reg r -> ch_local = quad*4+r (tile0) / 16+quad*4+r (tile1), col l16 = edge
        *reinterpret_cast<f32x4*>(&msgS[wid][l16][quad * 4])      = v0;
        *reinterpret_cast<f32x4*>(&msgS[wid][l16][16 + quad * 4]) = v1;

        // ---- run-walk reduction: lane = channel (coalesced atomics) ----
        // wave-local data: no __syncthreads needed (compiler inserts lgkmcnt waits)
        float racc = 0.f; int curd = -1;
        #pragma unroll
        for (int i = 0; i < 8; ++i) {
            int row = 8 * half + i;
            float v = msgS[wid][row][c32];
            int d = dsts[wid][row];
            if (i == 0) { curd = d; racc = v; }
            else if (d != curd) {
                atomicAdd(aggr + (size_t)curd * 128 + 32 * wid + c32, racc);
                curd = d; racc = v;
            } else racc += v;
        }
        atomicAdd(aggr + (size_t)curd * 128 + 32 * wid + c32, racc);
    }
}

// ---------------- node stream: out = aggr + Proot + bias; BN partials ----------------
__global__ __launch_bounds__(256) void node_stream_kernel(
    const __bf16* __restrict__ P, const float* __restrict__ bias,
    float* __restrict__ out, float* __restrict__ stats, int N_)
{
    __shared__ float redS[8][32][8];
    const int c4  = threadIdx.x & 31;
    const int grp = threadIdx.x >> 5;
    float4 bb = reinterpret_cast<const float4*>(bias)[c4];
    float ps[4] = {0.f, 0.f, 0.f, 0.f}, pq[4] = {0.f, 0.f, 0.f, 0.f};

    for (int n = blockIdx.x * 8 + grp; n < N_; n += gridDim.x * 8) {
        float4 v = reinterpret_cast<float4*>(out)[(size_t)n * 32 + c4];
        bf16x4 pr = *reinterpret_cast<const bf16x4*>(P + (size_t)n * 512 + 384 + c4 * 4);
        v.x += (float)pr[0] + bb.x;
        v.y += (float)pr[1] + bb.y;
        v.z += (float)pr[2] + bb.z;
        v.w += (float)pr[3] + bb.w;
        reinterpret_cast<float4*>(out)[(size_t)n * 32 + c4] = v;
        ps[0] += v.x; ps[1] += v.y; ps[2] += v.z; ps[3] += v.w;
        pq[0] += v.x * v.x; pq[1] += v.y * v.y; pq[2] += v.z * v.z; pq[3] += v.w * v.w;
    }
    #pragma unroll
    for (int j = 0; j < 4; ++j) { redS[grp][c4][j] = ps[j]; redS[grp][c4][4 + j] = pq[j]; }
    __syncthreads();
    {
        const int cc = threadIdx.x & 31, jj = threadIdx.x >> 5;
        float s = 0.f;
        #pragma unroll
        for (int k = 0; k < 8; ++k) s += redS[k][cc][jj];
        if (jj < 4) atomicAdd(&stats[cc * 4 + jj], s);
        else        atomicAdd(&stats[128 + cc * 4 + (jj - 4)], s);
    }
}

// ---------------- BN finalize ----------------
__global__ void bn_kernel(float* __restrict__ out, const float* __restrict__ stats,
                          const float* __restrict__ gamma, const float* __restrict__ beta,
                          float invN, int total4)
{
    int i = blockIdx.x * blockDim.x + threadIdx.x;
    if (i >= total4) return;
    int c0 = (i & 31) * 4;
    float4 v = reinterpret_cast<float4*>(out)[i];
    float o[4] = {v.x, v.y, v.z, v.w};
    #pragma unroll
    for (int j = 0; j < 4; ++j) {
        int c = c0 + j;
        float mean  = stats[c] * invN;
        float var   = stats[128 + c] * invN - mean * mean;
        float scale = gamma[c] * rsqrtf(var + BN_EPS);
        o[j] = (o[j] - mean) * scale + beta[c];
    }
    v.x = o[0]; v.y = o[1]; v.z = o[2]; v.w = o[3];
    reinterpret_cast<float4*>(out)[i] = v;
}

extern "C" void kernel_launch(void* const* d_in, const int* in_sizes, int n_in,
                              void* d_out, int out_size, void* d_ws, size_t ws_size,
                              hipStream_t stream)
{
    const float* x     = (const float*)d_in[0];
    const int*   eidx  = (const int*)d_in[1];
    const float* eattr = (const float*)d_in[2];
    const float* W1    = (const float*)d_in[3];
    const float* b1    = (const float*)d_in[4];
    const float* W2    = (const float*)d_in[5];
    const float* b2    = (const float*)d_in[6];
    const float* We    = (const float*)d_in[7];
    const float* be    = (const float*)d_in[8];
    const float* Wroot = (const float*)d_in[9];
    const float* bias  = (const float*)d_in[10];
    const float* gamma = (const float*)d_in[11];
    const float* beta  = (const float*)d_in[12];

    const int N_ = in_sizes[0] / 128;
    const int E_ = in_sizes[1] / 2;

    char* ws = (char*)d_ws;
    size_t off = 0;
    __bf16* P     = (__bf16*)(ws + off); off += (size_t)N_ * 512 * 2;
    __bf16* WcatT = (__bf16*)(ws + off); off += 512 * 128 * 2;
    __bf16* W2T   = (__bf16*)(ws + off); off += 128 * 128 * 2;
    __bf16* WeeT  = (__bf16*)(ws + off); off += 128 * 32 * 2;
    off = (off + 15) & ~(size_t)15;
    float* stats  = (float*)(ws + off);  off += 256 * 4;       // stats+count: one memset
    int* count    = (int*)(ws + off);    off += (size_t)N_ * 4;
    size_t zero_bytes = 256 * 4 + (size_t)N_ * 4;
    int* cursor   = (int*)(ws + off);    off += (size_t)N_ * 4;
    int* bsums    = (int*)(ws + off);    off += 64 * 4;
    off = (off + 15) & ~(size_t)15;
    int4* edgesS  = (int4*)(ws + off);   off += (size_t)E_ * 16;

    float* out = (float*)d_out;

    hipMemsetAsync(out, 0, (size_t)out_size * sizeof(float), stream);
    hipMemsetAsync(stats, 0, zero_bytes, stream);

    int wtot = 512 * 128 + 128 * 128 + 128 * 32;
    int wblocks = (wtot + 255) / 256;
    int eblocks = (E_ + 255) / 256;
    prep_hist_kernel<<<wblocks + eblocks, 256, 0, stream>>>(W1, W2, We, Wroot,
                                                            WcatT, W2T, WeeT,
                                                            eidx, count, E_, wblocks);

    int nb = (N_ + 4095) / 4096;
    scanA_kernel<<<nb, 1024, 0, stream>>>(count, cursor, bsums, N_);
    scanB_kernel<<<nb, 1024, 0, stream>>>(cursor, bsums, N_);
    scatter_kernel<<<eblocks, 256, 0, stream>>>(eidx, cursor, edgesS, E_);

    precompute_kernel<<<(N_ + 63) / 64, 256, 0, stream>>>(x, WcatT, P, N_);

    int nchunks = (E_ + 15) / 16;
    edge_kernel<<<2048, 256, 0, stream>>>(P, edgesS, eattr,
                                          W2T, b2, WeeT, b1, be, out, E_, nchunks);

    node_stream_kernel<<<512, 256, 0, stream>>>(P, bias, out, stats, N_);

    bn_kernel<<<(N_ * 32 + 255) / 256, 256, 0, stream>>>(out, stats, gamma, beta,
                                                         1.0f / (float)N_, N_ * 32);
}

// Round 8
// 522.316 us; speedup vs baseline: 2.3224x; 1.0427x over previous
//
#include <hip/hip_runtime.h>

typedef __bf16 bf16x8 __attribute__((ext_vector_type(8)));
typedef __bf16 bf16x4 __attribute__((ext_vector_type(4)));
typedef float  f32x4  __attribute__((ext_vector_type(4)));

#define BN_EPS 1e-5f

__device__ __forceinline__ float mish_f(float x) {
    float xc = fminf(x, 30.0f);
    float u = __expf(xc);
    float num = u * (u + 2.0f);
    return x * __fdividef(num, num + 2.0f);
}

// ---------------- fused prep: weights -> B^T bf16  +  dst histogram ----------------
// WcatT[512][128]: n<128 -> W1 rows 0..127 (x_i) | n<256 -> W1 rows 128..255 (x_j)
//                  n<384 -> We rows 16..143 (x_j) | n<512 -> Wroot
// W2T[128][128]; WeeT[128][32] (k<16 -> We rows 0..15 (eattr), else 0)
__global__ void prep_hist_kernel(const float* __restrict__ W1, const float* __restrict__ W2,
                                 const float* __restrict__ We, const float* __restrict__ Wr,
                                 __bf16* __restrict__ WcatT, __bf16* __restrict__ W2T,
                                 __bf16* __restrict__ WeeT,
                                 const int* __restrict__ eidx, int* __restrict__ count,
                                 int E_, int wblocks) {
    if ((int)blockIdx.x < wblocks) {
        int i = blockIdx.x * 256 + threadIdx.x;
        if (i < 512 * 128) {
            int n = i >> 7, k = i & 127;
            float v;
            if (n < 128)      v = W1[k * 128 + n];
            else if (n < 256) v = W1[(128 + k) * 128 + (n - 128)];
            else if (n < 384) v = We[(16 + k) * 128 + (n - 256)];
            else              v = Wr[k * 128 + (n - 384)];
            WcatT[(size_t)n * 128 + k] = (__bf16)v;
        } else if (i < 512 * 128 + 128 * 128) {
            int j = i - 512 * 128;
            int n = j >> 7, k = j & 127;
            W2T[n * 128 + k] = (__bf16)W2[k * 128 + n];
        } else if (i < 512 * 128 + 128 * 128 + 128 * 32) {
            int j = i - (512 * 128 + 128 * 128);
            int n = j >> 5, k = j & 31;
            WeeT[n * 32 + k] = (k < 16) ? (__bf16)We[k * 128 + n] : (__bf16)0.0f;
        }
    } else {
        int e = (blockIdx.x - wblocks) * 256 + threadIdx.x;
        if (e < E_) atomicAdd(&count[eidx[E_ + e]], 1);
    }
}

// ---------------- counting sort scan (parallel) ----------------
__global__ __launch_bounds__(1024) void scanA_kernel(const int* __restrict__ count,
                                                     int* __restrict__ cursor,
                                                     int* __restrict__ bsums, int Nn) {
    __shared__ int waveS[16];
    const int t = threadIdx.x;
    const int lane = t & 63;
    const int wv = t >> 6;
    const int i0 = blockIdx.x * 4096 + t * 4;
    int c0 = 0, c1 = 0, c2 = 0, c3 = 0;
    if (i0 + 3 < Nn) {
        int4 c = *reinterpret_cast<const int4*>(count + i0);
        c0 = c.x; c1 = c.y; c2 = c.z; c3 = c.w;
    } else if (i0 < Nn) {
        c0 = count[i0];
        if (i0 + 1 < Nn) c1 = count[i0 + 1];
        if (i0 + 2 < Nn) c2 = count[i0 + 2];
    }
    int s1 = c0 + c1, s2 = s1 + c2, tot = s2 + c3;
    int x = tot;
    #pragma unroll
    for (int s = 1; s < 64; s <<= 1) {
        int y = __shfl(x, (lane >= s) ? (lane - s) : lane);
        if (lane >= s) x += y;
    }
    if (lane == 63) waveS[wv] = x;
    __syncthreads();
    if (t == 0) {
        int run = 0;
        #pragma unroll
        for (int w = 0; w < 16; ++w) { int v = waveS[w]; waveS[w] = run; run += v; }
        bsums[blockIdx.x] = run;
    }
    __syncthreads();
    int excl = waveS[wv] + (x - tot);
    if (i0 + 3 < Nn) {
        int4 o; o.x = excl; o.y = excl + c0; o.z = excl + s1; o.w = excl + s2;
        *reinterpret_cast<int4*>(cursor + i0) = o;
    } else if (i0 < Nn) {
        cursor[i0] = excl;
        if (i0 + 1 < Nn) cursor[i0 + 1] = excl + c0;
        if (i0 + 2 < Nn) cursor[i0 + 2] = excl + s1;
    }
}

__global__ __launch_bounds__(1024) void scanB_kernel(int* __restrict__ cursor,
                                                     const int* __restrict__ bsums, int Nn) {
    __shared__ int offS;
    const int b = blockIdx.x;
    if (threadIdx.x == 0) {
        int s = 0;
        for (int i = 0; i < b; ++i) s += bsums[i];
        offS = s;
    }
    __syncthreads();
    const int o = offS;
    if (b == 0) return;
    const int i0 = b * 4096 + threadIdx.x * 4;
    if (i0 + 3 < Nn) {
        int4 v = *reinterpret_cast<int4*>(cursor + i0);
        v.x += o; v.y += o; v.z += o; v.w += o;
        *reinterpret_cast<int4*>(cursor + i0) = v;
    } else {
        #pragma unroll
        for (int j = 0; j < 4; ++j) if (i0 + j < Nn) cursor[i0 + j] += o;
    }
}

// ---------------- fused: scatter (sort chain) + precompute (weight chain) ----------------
// scatter blocks: edgesS[p] = (dst, src, perm, 0)
// precompute blocks: P[n][384] = x[n] @ [W1a|W1b|We_x] (bf16), out[n] = x[n]@Wroot + bias (fp32)
__global__ __launch_bounds__(256) void scatter_precomp_kernel(
    const int* __restrict__ eidx, int* __restrict__ cursor, int4* __restrict__ edgesS,
    int E_, int sblocks,
    const float* __restrict__ x, const __bf16* __restrict__ WcatT,
    const float* __restrict__ bias,
    __bf16* __restrict__ P, float* __restrict__ out, int N_)
{
    if ((int)blockIdx.x < sblocks) {
        int e = blockIdx.x * 256 + threadIdx.x;
        if (e < E_) {
            int d = eidx[E_ + e];
            int p = atomicAdd(&cursor[d], 1);
            edgesS[p] = make_int4(d, eidx[e], e, 0);
        }
        return;
    }
    const int bb = blockIdx.x - sblocks;
    const int wid  = threadIdx.x >> 6;
    const int lane = threadIdx.x & 63;
    const int quad = lane >> 4;
    const int l16  = lane & 15;

    int rl = bb * 64 + wid * 16 + l16;
    if (rl > N_ - 1) rl = N_ - 1;

    bf16x8 a[4];
    #pragma unroll
    for (int kt = 0; kt < 4; ++kt) {
        const float4* p = reinterpret_cast<const float4*>(x + (size_t)rl * 128 + kt * 32 + quad * 8);
        float4 v0 = p[0], v1 = p[1];
        a[kt][0] = (__bf16)v0.x; a[kt][1] = (__bf16)v0.y; a[kt][2] = (__bf16)v0.z; a[kt][3] = (__bf16)v0.w;
        a[kt][4] = (__bf16)v1.x; a[kt][5] = (__bf16)v1.y; a[kt][6] = (__bf16)v1.z; a[kt][7] = (__bf16)v1.w;
    }

    const f32x4 fz4 = {0.f, 0.f, 0.f, 0.f};
    #pragma unroll
    for (int g = 0; g < 4; ++g) {
        f32x4 acc[8];
        #pragma unroll
        for (int nt = 0; nt < 8; ++nt) acc[nt] = fz4;
        #pragma unroll
        for (int kt = 0; kt < 4; ++kt) {
            #pragma unroll
            for (int nt = 0; nt < 8; ++nt) {
                bf16x8 b = *reinterpret_cast<const bf16x8*>(
                    WcatT + (size_t)((g * 8 + nt) * 16 + l16) * 128 + kt * 32 + quad * 8);
                acc[nt] = __builtin_amdgcn_mfma_f32_16x16x32_bf16(a[kt], b, acc[nt], 0, 0, 0);
            }
        }
        if (g < 3) {
            #pragma unroll
            for (int nt = 0; nt < 8; ++nt) {
                #pragma unroll
                for (int r = 0; r < 4; ++r) {
                    int row = bb * 64 + wid * 16 + quad * 4 + r;
                    if (row < N_)
                        P[(size_t)row * 384 + g * 128 + nt * 16 + l16] = (__bf16)acc[nt][r];
                }
            }
        } else {
            #pragma unroll
            for (int nt = 0; nt < 8; ++nt) {
                float bc = bias[nt * 16 + l16];
                #pragma unroll
                for (int r = 0; r < 4; ++r) {
                    int row = bb * 64 + wid * 16 + quad * 4 + r;
                    if (row < N_)
                        out[(size_t)row * 128 + nt * 16 + l16] = acc[nt][r] + bc;
                }
            }
        }
    }
}

// ---------------- main edge kernel ----------------
// Single barrier per chunk: h1s/eattrS double-buffered; msgS/dsts wave-local.
// msg computed TRANSPOSED (D[ch][edge]) via A=W2^T frags, B=h1 rows from LDS,
// staged to wave-local LDS [edge][ch_local], reduced run-walk with lane=channel
// -> wave-coalesced atomics.
__global__ __launch_bounds__(256, 4) void edge_kernel(
    const __bf16* __restrict__ P,
    const int4* __restrict__ edgesS,
    const float* __restrict__ eattr,
    const __bf16* __restrict__ W2T, const float* __restrict__ b2,
    const __bf16* __restrict__ WeeT,
    const float* __restrict__ b1, const float* __restrict__ be,
    float* __restrict__ aggr, int E_, int nchunks)
{
    __shared__ __align__(16) __bf16 h1s[2][16][136];
    __shared__ __align__(16) __bf16 eattrS[2][16][16];
    __shared__ __align__(16) float msgS[4][16][36];
    __shared__ int dsts[4][16];

    const int wid  = threadIdx.x >> 6;
    const int lane = threadIdx.x & 63;
    const int quad = lane >> 4;
    const int l16  = lane & 15;
    const int half = lane >> 5;
    const int c32  = lane & 31;

    const int tb0 = 32 * wid;
    const int tb1 = 32 * wid + 16;
    const int chA = 32 * wid + quad * 8;

    // ---- resident A fragments: W2^T (ch x k) and WeeT (ch x k) ----
    bf16x8 aw2[4][2], awe[2];
    #pragma unroll
    for (int kt = 0; kt < 4; ++kt) {
        aw2[kt][0] = *reinterpret_cast<const bf16x8*>(W2T + (tb0 + l16) * 128 + kt * 32 + quad * 8);
        aw2[kt][1] = *reinterpret_cast<const bf16x8*>(W2T + (tb1 + l16) * 128 + kt * 32 + quad * 8);
    }
    awe[0] = *reinterpret_cast<const bf16x8*>(WeeT + (tb0 + l16) * 32 + quad * 8);
    awe[1] = *reinterpret_cast<const bf16x8*>(WeeT + (tb1 + l16) * 32 + quad * 8);

    const f32x4 b2v0 = *reinterpret_cast<const f32x4*>(b2 + tb0 + quad * 4);
    const f32x4 b2v1 = *reinterpret_cast<const f32x4*>(b2 + tb1 + quad * 4);
    const f32x4 bev0 = *reinterpret_cast<const f32x4*>(be + tb0 + quad * 4);
    const f32x4 bev1 = *reinterpret_cast<const f32x4*>(be + tb1 + quad * 4);
    const f32x4 b1a = *reinterpret_cast<const f32x4*>(b1 + chA);
    const f32x4 b1b = *reinterpret_cast<const f32x4*>(b1 + chA + 4);
    float b1v[8] = { b1a[0], b1a[1], b1a[2], b1a[3], b1b[0], b1b[1], b1b[2], b1b[3] };

    const f32x4 fz4 = {0.f, 0.f, 0.f, 0.f};
    int pbuf = 0;

    for (int ch = blockIdx.x; ch < nchunks; ch += gridDim.x) {
        const int e0 = ch * 16;
        int em = e0 + l16; if (em > E_ - 1) em = E_ - 1;
        const int4 er = edgesS[em];
        const int dst_m = er.x, src_m = er.y, pm = er.z;
        if (quad == 0) dsts[wid][l16] = dst_m;

        // ---- wave 0 stages eattr -> LDS bf16 (edge l16, k = quad*4..+4) ----
        if (wid == 0) {
            float4 v = *reinterpret_cast<const float4*>(eattr + (size_t)pm * 16 + quad * 4);
            bf16x4 o; o[0] = (__bf16)v.x; o[1] = (__bf16)v.y; o[2] = (__bf16)v.z; o[3] = (__bf16)v.w;
            *reinterpret_cast<bf16x4*>(&eattrS[pbuf][l16][quad * 4]) = o;
        }

        // ---- h1 = mish(Pa[dst] + Pb[src] + b1), row layout -> LDS ----
        bf16x8 pav = *reinterpret_cast<const bf16x8*>(P + (size_t)dst_m * 384 + chA);
        bf16x8 pbv = *reinterpret_cast<const bf16x8*>(P + (size_t)src_m * 384 + 128 + chA);
        bf16x8 h1v;
        #pragma unroll
        for (int j = 0; j < 8; ++j)
            h1v[j] = (__bf16)mish_f((float)pav[j] + (float)pbv[j] + b1v[j]);
        *reinterpret_cast<bf16x8*>(&h1s[pbuf][l16][chA]) = h1v;

        // ---- Pe vector loads: 4 consecutive ch per tile ----
        bf16x4 pe0 = *reinterpret_cast<const bf16x4*>(P + (size_t)src_m * 384 + 256 + tb0 + quad * 4);
        bf16x4 pe1 = *reinterpret_cast<const bf16x4*>(P + (size_t)src_m * 384 + 256 + tb1 + quad * 4);

        __syncthreads();   // h1s[pbuf] + eattrS[pbuf] ready

        // ---- GEMM2 (transposed): D[ch][edge] ----
        f32x4 acc2[2] = {fz4, fz4};
        #pragma unroll
        for (int kt = 0; kt < 4; ++kt) {
            bf16x8 bf = *reinterpret_cast<const bf16x8*>(&h1s[pbuf][l16][kt * 32 + quad * 8]);
            acc2[0] = __builtin_amdgcn_mfma_f32_16x16x32_bf16(aw2[kt][0], bf, acc2[0], 0, 0, 0);
            acc2[1] = __builtin_amdgcn_mfma_f32_16x16x32_bf16(aw2[kt][1], bf, acc2[1], 0, 0, 0);
        }

        // ---- B-frag for ee from LDS (k = quad*8+j, real only k<16) ----
        bf16x8 ae;
        if (quad < 2) ae = *reinterpret_cast<const bf16x8*>(&eattrS[pbuf][l16][quad * 8]);
        else {
            #pragma unroll
            for (int j = 0; j < 8; ++j) ae[j] = (__bf16)0.0f;
        }
        f32x4 acce[2] = {fz4, fz4};
        acce[0] = __builtin_amdgcn_mfma_f32_16x16x32_bf16(awe[0], ae, acce[0], 0, 0, 0);
        acce[1] = __builtin_amdgcn_mfma_f32_16x16x32_bf16(awe[1], ae, acce[1], 0, 0, 0);

        f32x4 v0, v1;
        #pragma unroll
        for (int r = 0; r < 4; ++r) {
            float he0 = mish_f(acce[0][r] + (float)pe0[r] + bev0[r]);
            float he1 = mish_f(acce[1][r] + (float)pe1[r] + bev1[r]);
            v0[r] = (acc2[0][r] + b2v0[r]) * he0;
            v1[r] = (acc2[1][r] + b2v1[r]) * he1;
        }
        if (e0 + l16 >= E_) { v0 = fz4; v1 = fz4; }

        // ---- stage msg to wave-local LDS: [edge l16][ch_local] ----
        *reinterpret_cast<f32x4*>(&msgS[wid][l16][quad * 4])      = v0;
        *reinterpret_cast<f32x4*>(&msgS[wid][l16][16 + quad * 4]) = v1;

        // ---- run-walk reduction: lane = channel (coalesced atomics) ----
        float racc = 0.f; int curd = -1;
        #pragma unroll
        for (int i = 0; i < 8; ++i) {
            int row = 8 * half + i;
            float v = msgS[wid][row][c32];
            int d = dsts[wid][row];
            if (i == 0) { curd = d; racc = v; }
            else if (d != curd) {
                atomicAdd(aggr + (size_t)curd * 128 + 32 * wid + c32, racc);
                curd = d; racc = v;
            } else racc += v;
        }
        atomicAdd(aggr + (size_t)curd * 128 + 32 * wid + c32, racc);

        pbuf ^= 1;
    }
}

// ---------------- stats: per-channel sum & sumsq of out ----------------
__global__ __launch_bounds__(256) void stats_kernel(
    const float* __restrict__ out, float* __restrict__ stats, int N_)
{
    __shared__ float redS[8][32][8];
    const int c4  = threadIdx.x & 31;
    const int grp = threadIdx.x >> 5;
    float ps[4] = {0.f, 0.f, 0.f, 0.f}, pq[4] = {0.f, 0.f, 0.f, 0.f};

    for (int n = blockIdx.x * 8 + grp; n < N_; n += gridDim.x * 8) {
        float4 v = reinterpret_cast<const float4*>(out)[(size_t)n * 32 + c4];
        ps[0] += v.x; ps[1] += v.y; ps[2] += v.z; ps[3] += v.w;
        pq[0] += v.x * v.x; pq[1] += v.y * v.y; pq[2] += v.z * v.z; pq[3] += v.w * v.w;
    }
    #pragma unroll
    for (int j = 0; j < 4; ++j) { redS[grp][c4][j] = ps[j]; redS[grp][c4][4 + j] = pq[j]; }
    __syncthreads();
    {
        const int cc = threadIdx.x & 31, jj = threadIdx.x >> 5;
        float s = 0.f;
        #pragma unroll
        for (int k = 0; k < 8; ++k) s += redS[k][cc][jj];
        if (jj < 4) atomicAdd(&stats[cc * 4 + jj], s);
        else        atomicAdd(&stats[128 + cc * 4 + (jj - 4)], s);
    }
}

// ---------------- BN finalize ----------------
__global__ void bn_kernel(float* __restrict__ out, const float* __restrict__ stats,
                          const float* __restrict__ gamma, const float* __restrict__ beta,
                          float invN, int total4)
{
    int i = blockIdx.x * blockDim.x + threadIdx.x;
    if (i >= total4) return;
    int c0 = (i & 31) * 4;
    float4 v = reinterpret_cast<float4*>(out)[i];
    float o[4] = {v.x, v.y, v.z, v.w};
    #pragma unroll
    for (int j = 0; j < 4; ++j) {
        int c = c0 + j;
        float mean  = stats[c] * invN;
        float var   = stats[128 + c] * invN - mean * mean;
        float scale = gamma[c] * rsqrtf(var + BN_EPS);
        o[j] = (o[j] - mean) * scale + beta[c];
    }
    v.x = o[0]; v.y = o[1]; v.z = o[2]; v.w = o[3];
    reinterpret_cast<float4*>(out)[i] = v;
}

extern "C" void kernel_launch(void* const* d_in, const int* in_sizes, int n_in,
                              void* d_out, int out_size, void* d_ws, size_t ws_size,
                              hipStream_t stream)
{
    const float* x     = (const float*)d_in[0];
    const int*   eidx  = (const int*)d_in[1];
    const float* eattr = (const float*)d_in[2];
    const float* W1    = (const float*)d_in[3];
    const float* b1    = (const float*)d_in[4];
    const float* W2    = (const float*)d_in[5];
    const float* b2    = (const float*)d_in[6];
    const float* We    = (const float*)d_in[7];
    const float* be    = (const float*)d_in[8];
    const float* Wroot = (const float*)d_in[9];
    const float* bias  = (const float*)d_in[10];
    const float* gamma = (const float*)d_in[11];
    const float* beta  = (const float*)d_in[12];

    const int N_ = in_sizes[0] / 128;
    const int E_ = in_sizes[1] / 2;

    char* ws = (char*)d_ws;
    size_t off = 0;
    __bf16* P     = (__bf16*)(ws + off); off += (size_t)N_ * 384 * 2;
    __bf16* WcatT = (__bf16*)(ws + off); off += 512 * 128 * 2;
    __bf16* W2T   = (__bf16*)(ws + off); off += 128 * 128 * 2;
    __bf16* WeeT  = (__bf16*)(ws + off); off += 128 * 32 * 2;
    off = (off + 15) & ~(size_t)15;
    float* stats  = (float*)(ws + off);  off += 256 * 4;       // stats+count: one memset
    int* count    = (int*)(ws + off);    off += (size_t)N_ * 4;
    size_t zero_bytes = 256 * 4 + (size_t)N_ * 4;
    int* cursor   = (int*)(ws + off);    off += (size_t)N_ * 4;
    int* bsums    = (int*)(ws + off);    off += 64 * 4;
    off = (off + 15) & ~(size_t)15;
    int4* edgesS  = (int4*)(ws + off);   off += (size_t)E_ * 16;

    float* out = (float*)d_out;

    hipMemsetAsync(stats, 0, zero_bytes, stream);

    int wtot = 512 * 128 + 128 * 128 + 128 * 32;
    int wblocks = (wtot + 255) / 256;
    int eblocks = (E_ + 255) / 256;
    prep_hist_kernel<<<wblocks + eblocks, 256, 0, stream>>>(W1, W2, We, Wroot,
                                                            WcatT, W2T, WeeT,
                                                            eidx, count, E_, wblocks);

    int nb = (N_ + 4095) / 4096;
    scanA_kernel<<<nb, 1024, 0, stream>>>(count, cursor, bsums, N_);
    scanB_kernel<<<nb, 1024, 0, stream>>>(cursor, bsums, N_);

    int pblocks = (N_ + 63) / 64;
    scatter_precomp_kernel<<<eblocks + pblocks, 256, 0, stream>>>(
        eidx, cursor, edgesS, E_, eblocks, x, WcatT, bias, P, out, N_);

    int nchunks = (E_ + 15) / 16;
    edge_kernel<<<2048, 256, 0, stream>>>(P, edgesS, eattr,
                                          W2T, b2, WeeT, b1, be, out, E_, nchunks);

    stats_kernel<<<512, 256, 0, stream>>>(out, stats, N_);

    bn_kernel<<<(N_ * 32 + 255) / 256, 256, 0, stream>>>(out, stats, gamma, beta,
                                                         1.0f / (float)N_, N_ * 32);
}